// Round 1
// baseline (1233.492 us; speedup 1.0000x reference)
//
#include <hip/hip_runtime.h>

#define B_SZ 2048
#define N_SZ 64
#define H_SZ 256

typedef __bf16 bf16_t;
typedef bf16_t bf16x8 __attribute__((ext_vector_type(8)));
typedef bf16_t bf16x4 __attribute__((ext_vector_type(4)));
typedef float  f32x4  __attribute__((ext_vector_type(4)));

// ---- workspace layout (bytes) ----
#define OFF_WCAT 0                    // swz Wcat B-frags: 512x256 bf16
#define OFF_WG   262144               // swz gate weights: 768x768 bf16
#define OFF_AB   1441792              // Ab bf16 2048x64x128
#define OFF_HB   34996224             // hb bf16 2048x64x256
#define OFF_HB2  102105088            // hb2 bf16
#define OFF_INP  169213952            // inputs bf16 2048x64x512
#define OFF_STA  303431680            // starA f32 2048x256
#define OFF_STB  305528832            // starB f32

#define NH_EL 33554432   // 2048*64*256
#define NA_EL 16777216   // 2048*64*128

__device__ __forceinline__ f32x4 mfma16(bf16x8 a, bf16x8 b, f32x4 c) {
  return __builtin_amdgcn_mfma_f32_16x16x32_bf16(a, b, c, 0, 0, 0);
}
__device__ __forceinline__ float sigm_(float x) { return 1.0f / (1.0f + __expf(-x)); }
__device__ __forceinline__ float tanh_(float x) { return 2.0f / (1.0f + __expf(-2.0f * x)) - 1.0f; }

typedef const uint32_t __attribute__((address_space(1)))* gas_t;
typedef uint32_t __attribute__((address_space(3)))* las_t;
// async global->LDS, 16 B/lane; LDS dst = wave-uniform base + lane*16
__device__ __forceinline__ void gld_lds(const void* g, void* l) {
  __builtin_amdgcn_global_load_lds((gas_t)g, (las_t)l, 16, 0, 0);
}

// ---------- weight pre-swizzle into MFMA B-fragment order ----------
// B-frag element: n = lane&15, k = (lane>>4)*8 + j
__global__ void swz_kernel(const float* __restrict__ W_in, const float* __restrict__ W_out,
                           const float* __restrict__ w_ih, const float* __restrict__ w_hh,
                           bf16_t* __restrict__ ws) {
  const int f = blockIdx.x * blockDim.x + threadIdx.x;  // frag-lane id (90112 total)
  const float* src;
  bf16_t* dst;
  if (f < 16384) {            // Wcat: (((ng*8+kb)*8+nl)*64+lane)*8
    const int l = f & 63, rem = f >> 6;
    const int nl = rem & 7, rem2 = rem >> 3, kb = rem2 & 7, ng = rem2 >> 3;
    const int c = ng * 128 + nl * 16 + (l & 15);
    const int k = kb * 32 + ((l >> 4) << 3);
    src = (c < 256) ? (W_in + c * 256 + k) : (W_out + (c - 256) * 256 + k);
    dst = ws + (size_t)OFF_WCAT / 2 + (size_t)f * 8;
  } else {                    // Wg: (((ct*24+kb)*6 + g*2+nl)*64+lane)*8
    const int f2 = f - 16384;
    const int l = f2 & 63, rem = f2 >> 6;        // 0..1151
    const int fi = rem % 6, rem2 = rem / 6, kb = rem2 % 24, ct = rem2 / 24;
    const int g = fi >> 1, nl = fi & 1;
    const int rw = g * 256 + ct * 32 + nl * 16 + (l & 15);
    const int kq = (l >> 4) << 3;
    if (kb < 16) src = w_ih + rw * 512 + kb * 32 + kq;
    else         src = w_hh + rw * 256 + (kb - 16) * 32 + kq;
    dst = ws + (size_t)OFF_WG / 2 + (size_t)f2 * 8;
  }
  bf16x8 v;
  #pragma unroll
  for (int j = 0; j < 8; ++j) v[j] = (bf16_t)src[j];
  *(bf16x8*)dst = v;
}

// ---------- f32 -> bf16 conversion of hidden and A ----------
__global__ void convert_kernel(const float* __restrict__ hid, const float* __restrict__ A,
                               bf16_t* __restrict__ hb, bf16_t* __restrict__ ab) {
  const size_t i4 = ((size_t)blockIdx.x * blockDim.x + threadIdx.x) * 4;
  if (i4 < NH_EL) {
    const f32x4 v = *(const f32x4*)(hid + i4);
    bf16x4 o = {(bf16_t)v[0], (bf16_t)v[1], (bf16_t)v[2], (bf16_t)v[3]};
    *(bf16x4*)(hb + i4) = o;
  } else {
    const size_t j4 = i4 - NH_EL;
    const f32x4 v = *(const f32x4*)(A + j4);
    bf16x4 o = {(bf16_t)v[0], (bf16_t)v[1], (bf16_t)v[2], (bf16_t)v[3]};
    *(bf16x4*)(ab + j4) = o;
  }
}

// ---------- star init: star = sum_n hid*mask / sum(mask)  (f32, matches ref) ----------
__global__ void star_init_kernel(const float* __restrict__ hid, const float* __restrict__ gmask,
                                 float* __restrict__ star) {
  const int b = blockIdx.x, c = threadIdx.x;
  float len = 0.f, s = 0.f;
  for (int n = 0; n < 64; ++n) {
    const float m = gmask[(size_t)b * 64 + n];
    len += m;
    s += hid[((size_t)b * 64 + n) * 256 + c] * m;
  }
  star[(size_t)b * 256 + c] = s / len;
}

// ---------- K13: X = h@Wcat^T + b  (in LDS), then inputs = Acat@X + bias ----------
// grid (1024 mtiles, 4 ngroups); 256 thr; m-tile 128 rows = 2 batches
__launch_bounds__(256, 2)
__global__ void k13_kernel(const bf16_t* __restrict__ hb, const bf16_t* __restrict__ ab,
                           const bf16_t* __restrict__ swzWcat,
                           const float* __restrict__ b_in, const float* __restrict__ b_out,
                           const float* __restrict__ b_iah, const float* __restrict__ b_oah,
                           bf16_t* __restrict__ inputs) {
  extern __shared__ char lds[];
  bf16_t* stA = (bf16_t*)lds;                // 8 frags  = 8192 B
  bf16_t* stB = (bf16_t*)(lds + 8192);       // 8 frags  = 8192 B
  bf16_t* CT  = (bf16_t*)(lds + 16384);      // 128 x 136 bf16 = 34816 B (X^T)
  bf16_t* AbF = (bf16_t*)(lds + 51200);      // 16 frags = 16384 B
  const int mtile = blockIdx.x, ng = blockIdx.y;
  const int t = threadIdx.x, w = t >> 6, l = t & 63;
  const int q = l >> 4, l15 = l & 15;
  const int half = ng >> 1, b0 = mtile * 2;

  // stage Ab fragments for GEMM2 up front (async; barriers below cover completion)
  #pragma unroll
  for (int i = 0; i < 4; ++i) {
    const int fidx = w * 4 + i, mt = fidx >> 1, kb2 = fidx & 1;
    const int bloc = b0 + (mt >> 2), m = (mt & 3) * 16 + l15;
    const bf16_t* g = ab + ((size_t)(bloc * 64 + m) * 128 + half * 64 + kb2 * 32 + q * 8);
    gld_lds(g, AbF + fidx * 512);
  }

  // ---- GEMM1: X-tile (128 x 128), K=256 ----
  f32x4 acc[2][8] = {};
  #pragma unroll 1
  for (int kb = 0; kb < 8; ++kb) {
    #pragma unroll
    for (int i = 0; i < 4; ++i) {
      const int f = w * 4 + i;
      if (f < 8) {
        const bf16_t* g = hb + ((size_t)(mtile * 128 + f * 16 + l15) * 256 + kb * 32 + q * 8);
        gld_lds(g, stA + f * 512);
      } else {
        const int fb = f - 8;
        const bf16_t* g = swzWcat + ((size_t)(((ng * 8 + kb) * 8 + fb)) * 64 + l) * 8;
        gld_lds(g, stB + fb * 512);
      }
    }
    __syncthreads();
    const bf16x8 a0 = *(const bf16x8*)(stA + (2 * w) * 512 + l * 8);
    const bf16x8 a1 = *(const bf16x8*)(stA + (2 * w + 1) * 512 + l * 8);
    #pragma unroll
    for (int nt = 0; nt < 8; ++nt) {
      const bf16x8 bf = *(const bf16x8*)(stB + nt * 512 + l * 8);
      acc[0][nt] = mfma16(a0, bf, acc[0][nt]);
      acc[1][nt] = mfma16(a1, bf, acc[1][nt]);
    }
    __syncthreads();
  }
  // epilogue: bias + bf16, store X^T into CT
  #pragma unroll
  for (int nt = 0; nt < 8; ++nt) {
    const int cl = nt * 16 + l15, cg = ng * 128 + cl;
    const float bb = (cg < 256) ? b_in[cg] : b_out[cg - 256];
    #pragma unroll
    for (int mti = 0; mti < 2; ++mti) {
      const int kloc = w * 32 + mti * 16 + q * 4;
      bf16x4 v = {(bf16_t)(acc[mti][nt][0] + bb), (bf16_t)(acc[mti][nt][1] + bb),
                  (bf16_t)(acc[mti][nt][2] + bb), (bf16_t)(acc[mti][nt][3] + bb)};
      *(bf16x4*)(CT + cl * 136 + kloc) = v;
    }
  }
  __syncthreads();

  // ---- GEMM2: inputs-tile = Acat @ X (K=64, per-batch block) ----
  f32x4 acc2[2][8] = {};
  const int bblk = (w >> 1) * 64;
  #pragma unroll
  for (int kb2 = 0; kb2 < 2; ++kb2) {
    const bf16x8 a0 = *(const bf16x8*)(AbF + ((2 * w) * 2 + kb2) * 512 + l * 8);
    const bf16x8 a1 = *(const bf16x8*)(AbF + ((2 * w + 1) * 2 + kb2) * 512 + l * 8);
    #pragma unroll
    for (int nt = 0; nt < 8; ++nt) {
      const bf16x8 bf = *(const bf16x8*)(CT + (nt * 16 + l15) * 136 + bblk + kb2 * 32 + q * 8);
      acc2[0][nt] = mfma16(a0, bf, acc2[0][nt]);
      acc2[1][nt] = mfma16(a1, bf, acc2[1][nt]);
    }
  }
  const int bglob = b0 + (w >> 1);
  #pragma unroll
  for (int nt = 0; nt < 8; ++nt) {
    const int c512 = ng * 128 + nt * 16 + l15;
    const float bb = (c512 < 256) ? b_iah[c512] : b_oah[c512 - 256];
    #pragma unroll
    for (int mti = 0; mti < 2; ++mti)
      #pragma unroll
      for (int i = 0; i < 4; ++i) {
        const int mloc = (w & 1) * 32 + mti * 16 + q * 4 + i;
        inputs[((size_t)(bglob * 64 + mloc)) * 512 + c512] = (bf16_t)(acc2[mti][nt][i] + bb);
      }
  }
}

// ---------- K3: gates GEMM (K=512 inputs + 256 h) + GRU update ----------
// grid (1024 mtiles, 8 ctiles of 32); 256 thr
__launch_bounds__(256, 2)
__global__ void k3_kernel(const bf16_t* __restrict__ inputs, const bf16_t* __restrict__ hb,
                          const bf16_t* __restrict__ swzWg,
                          const float* __restrict__ b_ih, const float* __restrict__ b_hh,
                          bf16_t* __restrict__ hb2) {
  extern __shared__ char lds[];
  bf16_t* stA = (bf16_t*)lds;            // 8 frags = 8192 B
  bf16_t* stB = (bf16_t*)(lds + 8192);   // 6 frags = 6144 B
  const int mtile = blockIdx.x, ct = blockIdx.y;
  const int t = threadIdx.x, w = t >> 6, l = t & 63;
  const int q = l >> 4, l15 = l & 15;

  f32x4 accR[2][2] = {}, accZ[2][2] = {}, accNI[2][2] = {}, accNH[2][2] = {};
  #pragma unroll 1
  for (int kb = 0; kb < 24; ++kb) {
    if (w < 2) {
      #pragma unroll
      for (int i = 0; i < 4; ++i) {
        const int f = w * 4 + i;
        const int row = mtile * 128 + f * 16 + l15;
        const bf16_t* g = (kb < 16)
          ? inputs + ((size_t)row * 512 + kb * 32 + q * 8)
          : hb + ((size_t)row * 256 + (kb - 16) * 32 + q * 8);
        gld_lds(g, stA + f * 512);
      }
    } else {
      #pragma unroll
      for (int i = 0; i < 3; ++i) {
        const int fb = (w - 2) * 3 + i;
        const bf16_t* g = swzWg + ((size_t)((ct * 24 + kb) * 6 + fb) * 64 + l) * 8;
        gld_lds(g, stB + fb * 512);
      }
    }
    __syncthreads();
    bf16x8 a[2];
    a[0] = *(const bf16x8*)(stA + (2 * w) * 512 + l * 8);
    a[1] = *(const bf16x8*)(stA + (2 * w + 1) * 512 + l * 8);
    #pragma unroll
    for (int g3 = 0; g3 < 3; ++g3)
      #pragma unroll
      for (int nl = 0; nl < 2; ++nl) {
        const bf16x8 bf = *(const bf16x8*)(stB + (g3 * 2 + nl) * 512 + l * 8);
        #pragma unroll
        for (int mti = 0; mti < 2; ++mti) {
          if (g3 == 0)      accR[mti][nl] = mfma16(a[mti], bf, accR[mti][nl]);
          else if (g3 == 1) accZ[mti][nl] = mfma16(a[mti], bf, accZ[mti][nl]);
          else if (kb < 16) accNI[mti][nl] = mfma16(a[mti], bf, accNI[mti][nl]);
          else              accNH[mti][nl] = mfma16(a[mti], bf, accNH[mti][nl]);
        }
      }
    __syncthreads();
  }
  // epilogue: gates + GRU
  #pragma unroll
  for (int nl = 0; nl < 2; ++nl) {
    const int c = ct * 32 + nl * 16 + l15;
    const float brv = b_ih[c] + b_hh[c];
    const float bzv = b_ih[256 + c] + b_hh[256 + c];
    const float biv = b_ih[512 + c];
    const float bhv = b_hh[512 + c];
    #pragma unroll
    for (int mti = 0; mti < 2; ++mti)
      #pragma unroll
      for (int i = 0; i < 4; ++i) {
        const size_t m = (size_t)mtile * 128 + w * 32 + mti * 16 + q * 4 + i;
        const float r = sigm_(accR[mti][nl][i] + brv);
        const float z = sigm_(accZ[mti][nl][i] + bzv);
        const float nn = tanh_(accNI[mti][nl][i] + biv + r * (accNH[mti][nl][i] + bhv));
        const float ho = (float)hb[m * 256 + c];
        hb2[m * 256 + c] = (bf16_t)(nn + z * (ho - nn));
      }
  }
}

// ---------- K4: attention mix + star update (per batch) ----------
__launch_bounds__(256, 2)
__global__ void k4_kernel(const bf16_t* __restrict__ hsrc, const float* __restrict__ star_in,
                          const float* __restrict__ gmask,
                          bf16_t* __restrict__ hb_out, float* __restrict__ star_out,
                          float* __restrict__ out_h, float* __restrict__ out_star,
                          const int is_last) {
  __shared__ bf16_t lhm[64 * 264];
  __shared__ float le[64];
  const int b = blockIdx.x, t = threadIdx.x;
  const int n = t >> 2, qq = t & 3, cbase = qq * 64;

  float hv[64], sv[64];
  float dot = 0.f;
  #pragma unroll
  for (int j = 0; j < 8; ++j) {
    const bf16x8 v = *(const bf16x8*)(hsrc + ((size_t)b * 64 + n) * 256 + cbase + j * 8);
    #pragma unroll
    for (int i = 0; i < 8; ++i) hv[j * 8 + i] = (float)v[i];
  }
  #pragma unroll
  for (int j = 0; j < 16; ++j) {
    const f32x4 s4 = *(const f32x4*)(star_in + (size_t)b * 256 + cbase + j * 4);
    sv[j * 4 + 0] = s4[0]; sv[j * 4 + 1] = s4[1]; sv[j * 4 + 2] = s4[2]; sv[j * 4 + 3] = s4[3];
  }
  #pragma unroll
  for (int i = 0; i < 64; ++i) dot += hv[i] * sv[i];
  dot += __shfl_xor(dot, 1); dot += __shfl_xor(dot, 2);
  const float alpha = sigm_(dot * 0.0625f);
  float dot2 = 0.f;
  #pragma unroll
  for (int i = 0; i < 64; ++i) {
    hv[i] = (1.f - alpha) * hv[i] + alpha * sv[i];
    dot2 += hv[i] * sv[i];
  }
  dot2 += __shfl_xor(dot2, 1); dot2 += __shfl_xor(dot2, 2);
  const float e = __expf(dot2) * gmask[(size_t)b * 64 + n];
  if (qq == 0) le[n] = e;
  // store mixed h (bf16 into LDS for star; global out per step)
  #pragma unroll
  for (int j = 0; j < 8; ++j) {
    bf16x8 v;
    #pragma unroll
    for (int i = 0; i < 8; ++i) v[i] = (bf16_t)hv[j * 8 + i];
    *(bf16x8*)(lhm + n * 264 + cbase + j * 8) = v;
    if (is_last) {
      f32x4 o = {hv[j * 8 + 0], hv[j * 8 + 1], hv[j * 8 + 2], hv[j * 8 + 3]};
      f32x4 o2 = {hv[j * 8 + 4], hv[j * 8 + 5], hv[j * 8 + 6], hv[j * 8 + 7]};
      *(f32x4*)(out_h + ((size_t)b * 64 + n) * 256 + cbase + j * 8) = o;
      *(f32x4*)(out_h + ((size_t)b * 64 + n) * 256 + cbase + j * 8 + 4) = o2;
    } else {
      *(bf16x8*)(hb_out + ((size_t)b * 64 + n) * 256 + cbase + j * 8) = v;
    }
  }
  __syncthreads();
  float den = 1e-24f;
  for (int n2 = 0; n2 < 64; ++n2) den += le[n2];
  const int c = t;  // 0..255
  float s = 0.f;
  for (int n2 = 0; n2 < 64; ++n2) s += le[n2] * (float)lhm[n2 * 264 + c];
  const float sn = s / den;
  if (is_last) out_star[(size_t)b * 256 + c] = sn;
  else         star_out[(size_t)b * 256 + c] = sn;
}

extern "C" void kernel_launch(void* const* d_in, const int* in_sizes, int n_in,
                              void* d_out, int out_size, void* d_ws, size_t ws_size,
                              hipStream_t stream) {
  const float* A     = (const float*)d_in[0];
  const float* hid   = (const float*)d_in[1];
  const float* gmask = (const float*)d_in[2];
  const float* w_ih  = (const float*)d_in[3];
  const float* w_hh  = (const float*)d_in[4];
  const float* b_ih  = (const float*)d_in[5];
  const float* b_hh  = (const float*)d_in[6];
  const float* b_iah = (const float*)d_in[7];
  const float* b_oah = (const float*)d_in[8];
  const float* W_in  = (const float*)d_in[9];
  const float* b_in  = (const float*)d_in[10];
  const float* W_out = (const float*)d_in[11];
  const float* b_out = (const float*)d_in[12];
  float* out = (float*)d_out;
  char* ws = (char*)d_ws;

  bf16_t* swzWcat = (bf16_t*)(ws + OFF_WCAT);
  bf16_t* swzWg   = (bf16_t*)(ws + OFF_WG);
  bf16_t* ab      = (bf16_t*)(ws + OFF_AB);
  bf16_t* hb      = (bf16_t*)(ws + OFF_HB);
  bf16_t* hb2     = (bf16_t*)(ws + OFF_HB2);
  bf16_t* inputs  = (bf16_t*)(ws + OFF_INP);
  float*  starA   = (float*)(ws + OFF_STA);
  float*  starB   = (float*)(ws + OFF_STB);
  float* out_h    = out;
  float* out_star = out + (size_t)B_SZ * N_SZ * H_SZ;

  (void)hipFuncSetAttribute((const void*)k13_kernel,
                            hipFuncAttributeMaxDynamicSharedMemorySize, 67584);

  swz_kernel<<<352, 256, 0, stream>>>(W_in, W_out, w_ih, w_hh, (bf16_t*)ws);
  convert_kernel<<<49152, 256, 0, stream>>>(hid, A, hb, ab);
  star_init_kernel<<<2048, 256, 0, stream>>>(hid, gmask, starA);

  // step 0
  k13_kernel<<<dim3(1024, 4), 256, 67584, stream>>>(hb, ab, swzWcat, b_in, b_out, b_iah, b_oah, inputs);
  k3_kernel<<<dim3(1024, 8), 256, 14336, stream>>>(inputs, hb, swzWg, b_ih, b_hh, hb2);
  k4_kernel<<<2048, 256, 0, stream>>>(hb2, starA, gmask, hb, starB, out_h, out_star, 0);
  // step 1
  k13_kernel<<<dim3(1024, 4), 256, 67584, stream>>>(hb, ab, swzWcat, b_in, b_out, b_iah, b_oah, inputs);
  k3_kernel<<<dim3(1024, 8), 256, 14336, stream>>>(inputs, hb, swzWg, b_ih, b_hh, hb2);
  k4_kernel<<<2048, 256, 0, stream>>>(hb2, starB, gmask, hb, starA, out_h, out_star, 1);
}

// Round 2
// 1199.156 us; speedup vs baseline: 1.0286x; 1.0286x over previous
//
#include <hip/hip_runtime.h>

#define B_SZ 2048
#define N_SZ 64
#define H_SZ 256

typedef __bf16 bf16_t;
typedef bf16_t bf16x8 __attribute__((ext_vector_type(8)));
typedef bf16_t bf16x4 __attribute__((ext_vector_type(4)));
typedef float  f32x4  __attribute__((ext_vector_type(4)));

// ---- workspace layout (bytes) ----
#define OFF_WCAT 0                    // swz Wcat B-frags: 512x256 bf16
#define OFF_WG   262144               // swz gate weights: 768x768 bf16
#define OFF_AB   1441792              // Ab bf16 2048x64x128
#define OFF_HB   34996224             // hb bf16 2048x64x256
#define OFF_HB2  102105088            // hb2 bf16
#define OFF_INP  169213952            // inputs bf16 2048x64x512
#define OFF_STA  303431680            // starA f32 2048x256
#define OFF_STB  305528832            // starB f32

#define NH_EL 33554432   // 2048*64*256
#define NA_EL 16777216   // 2048*64*128

__device__ __forceinline__ f32x4 mfma16(bf16x8 a, bf16x8 b, f32x4 c) {
  return __builtin_amdgcn_mfma_f32_16x16x32_bf16(a, b, c, 0, 0, 0);
}
__device__ __forceinline__ float sigm_(float x) { return 1.0f / (1.0f + __expf(-x)); }
__device__ __forceinline__ float tanh_(float x) { return 2.0f / (1.0f + __expf(-2.0f * x)) - 1.0f; }

typedef const uint32_t __attribute__((address_space(1)))* gas_t;
typedef uint32_t __attribute__((address_space(3)))* las_t;
// async global->LDS, 16 B/lane; LDS dst = wave-uniform base + lane*16
__device__ __forceinline__ void gld_lds(const void* g, void* l) {
  __builtin_amdgcn_global_load_lds((gas_t)g, (las_t)l, 16, 0, 0);
}

// ---------- weight pre-swizzle into MFMA B-fragment order ----------
// B-frag element: n = lane&15, k = (lane>>4)*8 + j
__global__ void swz_kernel(const float* __restrict__ W_in, const float* __restrict__ W_out,
                           const float* __restrict__ w_ih, const float* __restrict__ w_hh,
                           bf16_t* __restrict__ ws) {
  const int f = blockIdx.x * blockDim.x + threadIdx.x;  // frag-lane id (90112 total)
  const float* src;
  bf16_t* dst;
  if (f < 16384) {            // Wcat: (((ng*8+kb)*8+nl)*64+lane)*8
    const int l = f & 63, rem = f >> 6;
    const int nl = rem & 7, rem2 = rem >> 3, kb = rem2 & 7, ng = rem2 >> 3;
    const int c = ng * 128 + nl * 16 + (l & 15);
    const int k = kb * 32 + ((l >> 4) << 3);
    src = (c < 256) ? (W_in + c * 256 + k) : (W_out + (c - 256) * 256 + k);
    dst = ws + (size_t)OFF_WCAT / 2 + (size_t)f * 8;
  } else {                    // Wg (ct4 layout): (((ct*24+kb)*12 + g*4+nl)*64+lane)*8
    const int f2 = f - 16384;
    const int l = f2 & 63, rem = f2 >> 6;        // 0..1151
    const int fi = rem % 12, rem2 = rem / 12, kb = rem2 % 24, ct = rem2 / 24;
    const int g = fi >> 2, nl = fi & 3;
    const int rw = g * 256 + ct * 64 + nl * 16 + (l & 15);
    const int kq = (l >> 4) << 3;
    if (kb < 16) src = w_ih + rw * 512 + kb * 32 + kq;
    else         src = w_hh + rw * 256 + (kb - 16) * 32 + kq;
    dst = ws + (size_t)OFF_WG / 2 + (size_t)f2 * 8;
  }
  bf16x8 v;
  #pragma unroll
  for (int j = 0; j < 8; ++j) v[j] = (bf16_t)src[j];
  *(bf16x8*)dst = v;
}

// ---------- f32 -> bf16 conversion of hidden and A ----------
__global__ void convert_kernel(const float* __restrict__ hid, const float* __restrict__ A,
                               bf16_t* __restrict__ hb, bf16_t* __restrict__ ab) {
  const size_t i4 = ((size_t)blockIdx.x * blockDim.x + threadIdx.x) * 4;
  if (i4 < NH_EL) {
    const f32x4 v = *(const f32x4*)(hid + i4);
    bf16x4 o = {(bf16_t)v[0], (bf16_t)v[1], (bf16_t)v[2], (bf16_t)v[3]};
    *(bf16x4*)(hb + i4) = o;
  } else {
    const size_t j4 = i4 - NH_EL;
    const f32x4 v = *(const f32x4*)(A + j4);
    bf16x4 o = {(bf16_t)v[0], (bf16_t)v[1], (bf16_t)v[2], (bf16_t)v[3]};
    *(bf16x4*)(ab + j4) = o;
  }
}

// ---------- star init: star = sum_n hid*mask / sum(mask)  (f32, matches ref) ----------
__global__ void star_init_kernel(const float* __restrict__ hid, const float* __restrict__ gmask,
                                 float* __restrict__ star) {
  const int b = blockIdx.x, c = threadIdx.x;
  float len = 0.f, s = 0.f;
  for (int n = 0; n < 64; ++n) {
    const float m = gmask[(size_t)b * 64 + n];
    len += m;
    s += hid[((size_t)b * 64 + n) * 256 + c] * m;
  }
  star[(size_t)b * 256 + c] = s / len;
}

// ---------- K13: X = h@Wcat^T + b  (in LDS), then inputs = Acat@X + bias ----------
// 1D grid 4096 (XCD-chunk swizzled -> mtile, ng); 256 thr; m-tile 128 rows = 2 batches
__launch_bounds__(256, 2)
__global__ void k13_kernel(const bf16_t* __restrict__ hb, const bf16_t* __restrict__ ab,
                           const bf16_t* __restrict__ swzWcat,
                           const float* __restrict__ b_in, const float* __restrict__ b_out,
                           const float* __restrict__ b_iah, const float* __restrict__ b_oah,
                           bf16_t* __restrict__ inputs) {
  extern __shared__ char lds[];
  bf16_t* stA = (bf16_t*)lds;                // 8 frags  = 8192 B
  bf16_t* stB = (bf16_t*)(lds + 8192);       // 8 frags  = 8192 B
  bf16_t* CT  = (bf16_t*)(lds + 16384);      // 128 x 136 bf16 = 34816 B (X^T)
  bf16_t* AbF = (bf16_t*)(lds + 51200);      // 16 frags = 16384 B
  // XCD-chunked swizzle: 4 ng-blocks of one mtile land adjacent on one XCD
  const int lin = blockIdx.x;
  const int vid = (lin & 7) * 512 + (lin >> 3);
  const int mtile = vid >> 2, ng = vid & 3;
  const int t = threadIdx.x, w = t >> 6, l = t & 63;
  const int q = l >> 4, l15 = l & 15;
  const int half = ng >> 1, b0 = mtile * 2;

  // stage Ab fragments for GEMM2 up front (async; barriers below cover completion)
  #pragma unroll
  for (int i = 0; i < 4; ++i) {
    const int fidx = w * 4 + i, mt = fidx >> 1, kb2 = fidx & 1;
    const int bloc = b0 + (mt >> 2), m = (mt & 3) * 16 + l15;
    const bf16_t* g = ab + ((size_t)(bloc * 64 + m) * 128 + half * 64 + kb2 * 32 + q * 8);
    gld_lds(g, AbF + fidx * 512);
  }

  // ---- GEMM1: X-tile (128 x 128), K=256 ----
  f32x4 acc[2][8] = {};
  #pragma unroll 1
  for (int kb = 0; kb < 8; ++kb) {
    #pragma unroll
    for (int i = 0; i < 4; ++i) {
      const int f = w * 4 + i;
      if (f < 8) {
        const bf16_t* g = hb + ((size_t)(mtile * 128 + f * 16 + l15) * 256 + kb * 32 + q * 8);
        gld_lds(g, stA + f * 512);
      } else {
        const int fb = f - 8;
        const bf16_t* g = swzWcat + ((size_t)(((ng * 8 + kb) * 8 + fb)) * 64 + l) * 8;
        gld_lds(g, stB + fb * 512);
      }
    }
    __syncthreads();
    const bf16x8 a0 = *(const bf16x8*)(stA + (2 * w) * 512 + l * 8);
    const bf16x8 a1 = *(const bf16x8*)(stA + (2 * w + 1) * 512 + l * 8);
    #pragma unroll
    for (int nt = 0; nt < 8; ++nt) {
      const bf16x8 bf = *(const bf16x8*)(stB + nt * 512 + l * 8);
      acc[0][nt] = mfma16(a0, bf, acc[0][nt]);
      acc[1][nt] = mfma16(a1, bf, acc[1][nt]);
    }
    __syncthreads();
  }
  // epilogue: bias + bf16, store X^T into CT
  #pragma unroll
  for (int nt = 0; nt < 8; ++nt) {
    const int cl = nt * 16 + l15, cg = ng * 128 + cl;
    const float bb = (cg < 256) ? b_in[cg] : b_out[cg - 256];
    #pragma unroll
    for (int mti = 0; mti < 2; ++mti) {
      const int kloc = w * 32 + mti * 16 + q * 4;
      bf16x4 v = {(bf16_t)(acc[mti][nt][0] + bb), (bf16_t)(acc[mti][nt][1] + bb),
                  (bf16_t)(acc[mti][nt][2] + bb), (bf16_t)(acc[mti][nt][3] + bb)};
      *(bf16x4*)(CT + cl * 136 + kloc) = v;
    }
  }
  __syncthreads();

  // ---- GEMM2: inputs-tile = Acat @ X (K=64, per-batch block) ----
  f32x4 acc2[2][8] = {};
  const int bblk = (w >> 1) * 64;
  #pragma unroll
  for (int kb2 = 0; kb2 < 2; ++kb2) {
    const bf16x8 a0 = *(const bf16x8*)(AbF + ((2 * w) * 2 + kb2) * 512 + l * 8);
    const bf16x8 a1 = *(const bf16x8*)(AbF + ((2 * w + 1) * 2 + kb2) * 512 + l * 8);
    #pragma unroll
    for (int nt = 0; nt < 8; ++nt) {
      const bf16x8 bf = *(const bf16x8*)(CT + (nt * 16 + l15) * 136 + bblk + kb2 * 32 + q * 8);
      acc2[0][nt] = mfma16(a0, bf, acc2[0][nt]);
      acc2[1][nt] = mfma16(a1, bf, acc2[1][nt]);
    }
  }
  const int bglob = b0 + (w >> 1);
  #pragma unroll
  for (int nt = 0; nt < 8; ++nt) {
    const int c512 = ng * 128 + nt * 16 + l15;
    const float bb = (c512 < 256) ? b_iah[c512] : b_oah[c512 - 256];
    #pragma unroll
    for (int mti = 0; mti < 2; ++mti)
      #pragma unroll
      for (int i = 0; i < 4; ++i) {
        const int mloc = (w & 1) * 32 + mti * 16 + q * 4 + i;
        inputs[((size_t)(bglob * 64 + mloc)) * 512 + c512] = (bf16_t)(acc2[mti][nt][i] + bb);
      }
  }
}

// ---------- K3: gates GEMM (K=512 inputs + 256 h) + GRU update ----------
// 1D grid 4096 (XCD-chunk swizzled -> mtile, ct of 4); 256 thr; N-tile 64 H-cols
__launch_bounds__(256, 2)
__global__ void k3_kernel(const bf16_t* __restrict__ inputs, const bf16_t* __restrict__ hb,
                          const bf16_t* __restrict__ swzWg,
                          const float* __restrict__ b_ih, const float* __restrict__ b_hh,
                          bf16_t* __restrict__ hb2) {
  extern __shared__ char lds[];
  bf16_t* stA = (bf16_t*)lds;            // 8 frags  = 8192 B
  bf16_t* stB = (bf16_t*)(lds + 8192);   // 12 frags = 12288 B
  // XCD-chunked swizzle: 4 ct-blocks of one mtile land adjacent on one XCD
  const int lin = blockIdx.x;
  const int vid = (lin & 7) * 512 + (lin >> 3);
  const int mtile = vid >> 2, ct = vid & 3;
  const int t = threadIdx.x, w = t >> 6, l = t & 63;
  const int q = l >> 4, l15 = l & 15;

  f32x4 accR[2][4] = {}, accZ[2][4] = {}, accNI[2][4] = {}, accNH[2][4] = {};
  #pragma unroll 1
  for (int kb = 0; kb < 24; ++kb) {
    if (w < 2) {
      #pragma unroll
      for (int i = 0; i < 4; ++i) {
        const int f = w * 4 + i;
        const int row = mtile * 128 + f * 16 + l15;
        const bf16_t* g = (kb < 16)
          ? inputs + ((size_t)row * 512 + kb * 32 + q * 8)
          : hb + ((size_t)row * 256 + (kb - 16) * 32 + q * 8);
        gld_lds(g, stA + f * 512);
      }
    } else {
      #pragma unroll
      for (int i = 0; i < 6; ++i) {
        const int fb = (w - 2) * 6 + i;
        const bf16_t* g = swzWg + ((size_t)((ct * 24 + kb) * 12 + fb) * 64 + l) * 8;
        gld_lds(g, stB + fb * 512);
      }
    }
    __syncthreads();
    bf16x8 a[2];
    a[0] = *(const bf16x8*)(stA + (2 * w) * 512 + l * 8);
    a[1] = *(const bf16x8*)(stA + (2 * w + 1) * 512 + l * 8);
    #pragma unroll
    for (int g3 = 0; g3 < 3; ++g3)
      #pragma unroll
      for (int nl = 0; nl < 4; ++nl) {
        const bf16x8 bf = *(const bf16x8*)(stB + (g3 * 4 + nl) * 512 + l * 8);
        #pragma unroll
        for (int mti = 0; mti < 2; ++mti) {
          if (g3 == 0)      accR[mti][nl] = mfma16(a[mti], bf, accR[mti][nl]);
          else if (g3 == 1) accZ[mti][nl] = mfma16(a[mti], bf, accZ[mti][nl]);
          else if (kb < 16) accNI[mti][nl] = mfma16(a[mti], bf, accNI[mti][nl]);
          else              accNH[mti][nl] = mfma16(a[mti], bf, accNH[mti][nl]);
        }
      }
    __syncthreads();
  }
  // epilogue: gates + GRU
  #pragma unroll
  for (int nl = 0; nl < 4; ++nl) {
    const int c = ct * 64 + nl * 16 + l15;
    const float brv = b_ih[c] + b_hh[c];
    const float bzv = b_ih[256 + c] + b_hh[256 + c];
    const float biv = b_ih[512 + c];
    const float bhv = b_hh[512 + c];
    #pragma unroll
    for (int mti = 0; mti < 2; ++mti)
      #pragma unroll
      for (int i = 0; i < 4; ++i) {
        const size_t m = (size_t)mtile * 128 + w * 32 + mti * 16 + q * 4 + i;
        const float r = sigm_(accR[mti][nl][i] + brv);
        const float z = sigm_(accZ[mti][nl][i] + bzv);
        const float nn = tanh_(accNI[mti][nl][i] + biv + r * (accNH[mti][nl][i] + bhv));
        const float ho = (float)hb[m * 256 + c];
        hb2[m * 256 + c] = (bf16_t)(nn + z * (ho - nn));
      }
  }
}

// ---------- K4: attention mix + star update (per batch) ----------
__launch_bounds__(256, 2)
__global__ void k4_kernel(const bf16_t* __restrict__ hsrc, const float* __restrict__ star_in,
                          const float* __restrict__ gmask,
                          bf16_t* __restrict__ hb_out, float* __restrict__ star_out,
                          float* __restrict__ out_h, float* __restrict__ out_star,
                          const int is_last) {
  __shared__ bf16_t lhm[64 * 264];
  __shared__ float le[64];
  const int b = blockIdx.x, t = threadIdx.x;
  const int n = t >> 2, qq = t & 3, cbase = qq * 64;

  float hv[64], sv[64];
  float dot = 0.f;
  #pragma unroll
  for (int j = 0; j < 8; ++j) {
    const bf16x8 v = *(const bf16x8*)(hsrc + ((size_t)b * 64 + n) * 256 + cbase + j * 8);
    #pragma unroll
    for (int i = 0; i < 8; ++i) hv[j * 8 + i] = (float)v[i];
  }
  #pragma unroll
  for (int j = 0; j < 16; ++j) {
    const f32x4 s4 = *(const f32x4*)(star_in + (size_t)b * 256 + cbase + j * 4);
    sv[j * 4 + 0] = s4[0]; sv[j * 4 + 1] = s4[1]; sv[j * 4 + 2] = s4[2]; sv[j * 4 + 3] = s4[3];
  }
  #pragma unroll
  for (int i = 0; i < 64; ++i) dot += hv[i] * sv[i];
  dot += __shfl_xor(dot, 1); dot += __shfl_xor(dot, 2);
  const float alpha = sigm_(dot * 0.0625f);
  float dot2 = 0.f;
  #pragma unroll
  for (int i = 0; i < 64; ++i) {
    hv[i] = (1.f - alpha) * hv[i] + alpha * sv[i];
    dot2 += hv[i] * sv[i];
  }
  dot2 += __shfl_xor(dot2, 1); dot2 += __shfl_xor(dot2, 2);
  const float e = __expf(dot2) * gmask[(size_t)b * 64 + n];
  if (qq == 0) le[n] = e;
  // store mixed h (bf16 into LDS for star; global out per step)
  #pragma unroll
  for (int j = 0; j < 8; ++j) {
    bf16x8 v;
    #pragma unroll
    for (int i = 0; i < 8; ++i) v[i] = (bf16_t)hv[j * 8 + i];
    *(bf16x8*)(lhm + n * 264 + cbase + j * 8) = v;
    if (is_last) {
      f32x4 o = {hv[j * 8 + 0], hv[j * 8 + 1], hv[j * 8 + 2], hv[j * 8 + 3]};
      f32x4 o2 = {hv[j * 8 + 4], hv[j * 8 + 5], hv[j * 8 + 6], hv[j * 8 + 7]};
      *(f32x4*)(out_h + ((size_t)b * 64 + n) * 256 + cbase + j * 8) = o;
      *(f32x4*)(out_h + ((size_t)b * 64 + n) * 256 + cbase + j * 8 + 4) = o2;
    } else {
      *(bf16x8*)(hb_out + ((size_t)b * 64 + n) * 256 + cbase + j * 8) = v;
    }
  }
  __syncthreads();
  float den = 1e-24f;
  for (int n2 = 0; n2 < 64; ++n2) den += le[n2];
  const int c = t;  // 0..255
  float s = 0.f;
  for (int n2 = 0; n2 < 64; ++n2) s += le[n2] * (float)lhm[n2 * 264 + c];
  const float sn = s / den;
  if (is_last) out_star[(size_t)b * 256 + c] = sn;
  else         star_out[(size_t)b * 256 + c] = sn;
}

extern "C" void kernel_launch(void* const* d_in, const int* in_sizes, int n_in,
                              void* d_out, int out_size, void* d_ws, size_t ws_size,
                              hipStream_t stream) {
  const float* A     = (const float*)d_in[0];
  const float* hid   = (const float*)d_in[1];
  const float* gmask = (const float*)d_in[2];
  const float* w_ih  = (const float*)d_in[3];
  const float* w_hh  = (const float*)d_in[4];
  const float* b_ih  = (const float*)d_in[5];
  const float* b_hh  = (const float*)d_in[6];
  const float* b_iah = (const float*)d_in[7];
  const float* b_oah = (const float*)d_in[8];
  const float* W_in  = (const float*)d_in[9];
  const float* b_in  = (const float*)d_in[10];
  const float* W_out = (const float*)d_in[11];
  const float* b_out = (const float*)d_in[12];
  float* out = (float*)d_out;
  char* ws = (char*)d_ws;

  bf16_t* swzWcat = (bf16_t*)(ws + OFF_WCAT);
  bf16_t* swzWg   = (bf16_t*)(ws + OFF_WG);
  bf16_t* ab      = (bf16_t*)(ws + OFF_AB);
  bf16_t* hb      = (bf16_t*)(ws + OFF_HB);
  bf16_t* hb2     = (bf16_t*)(ws + OFF_HB2);
  bf16_t* inputs  = (bf16_t*)(ws + OFF_INP);
  float*  starA   = (float*)(ws + OFF_STA);
  float*  starB   = (float*)(ws + OFF_STB);
  float* out_h    = out;
  float* out_star = out + (size_t)B_SZ * N_SZ * H_SZ;

  (void)hipFuncSetAttribute((const void*)k13_kernel,
                            hipFuncAttributeMaxDynamicSharedMemorySize, 67584);

  swz_kernel<<<352, 256, 0, stream>>>(W_in, W_out, w_ih, w_hh, (bf16_t*)ws);
  convert_kernel<<<49152, 256, 0, stream>>>(hid, A, hb, ab);
  star_init_kernel<<<2048, 256, 0, stream>>>(hid, gmask, starA);

  // step 0
  k13_kernel<<<4096, 256, 67584, stream>>>(hb, ab, swzWcat, b_in, b_out, b_iah, b_oah, inputs);
  k3_kernel<<<4096, 256, 20480, stream>>>(inputs, hb, swzWg, b_ih, b_hh, hb2);
  k4_kernel<<<2048, 256, 0, stream>>>(hb2, starA, gmask, hb, starB, out_h, out_star, 0);
  // step 1
  k13_kernel<<<4096, 256, 67584, stream>>>(hb, ab, swzWcat, b_in, b_out, b_iah, b_oah, inputs);
  k3_kernel<<<4096, 256, 20480, stream>>>(inputs, hb, swzWg, b_ih, b_hh, hb2);
  k4_kernel<<<2048, 256, 0, stream>>>(hb2, starB, gmask, hb, starA, out_h, out_star, 1);
}

// Round 3
// 1098.331 us; speedup vs baseline: 1.1231x; 1.0918x over previous
//
#include <hip/hip_runtime.h>

#define B_SZ 2048
#define N_SZ 64
#define H_SZ 256

typedef __bf16 bf16_t;
typedef bf16_t bf16x8 __attribute__((ext_vector_type(8)));
typedef bf16_t bf16x4 __attribute__((ext_vector_type(4)));
typedef float  f32x4  __attribute__((ext_vector_type(4)));

// ---- workspace layout (bytes) ----
#define OFF_WCAT 0                    // swz Wcat B-frags: 512x256 bf16
#define OFF_WG   262144               // swz gate weights: 768x768 bf16
#define OFF_AB   1441792              // Ab bf16 2048x64x128
#define OFF_HB   34996224             // hb bf16 2048x64x256
#define OFF_HB2  102105088            // hb2 bf16
#define OFF_INP  169213952            // inputs bf16 2048x64x512
#define OFF_STA  303431680            // starA f32 2048x256
#define OFF_STB  305528832            // starB f32

#define NH_EL 33554432   // 2048*64*256
#define NA_EL 16777216   // 2048*64*128

__device__ __forceinline__ f32x4 mfma16(bf16x8 a, bf16x8 b, f32x4 c) {
  return __builtin_amdgcn_mfma_f32_16x16x32_bf16(a, b, c, 0, 0, 0);
}
__device__ __forceinline__ float sigm_(float x) { return 1.0f / (1.0f + __expf(-x)); }
__device__ __forceinline__ float tanh_(float x) { return 2.0f / (1.0f + __expf(-2.0f * x)) - 1.0f; }

typedef const uint32_t __attribute__((address_space(1)))* gas_t;
typedef uint32_t __attribute__((address_space(3)))* las_t;
// async global->LDS, 16 B/lane; LDS dst = wave-uniform base + lane*16
__device__ __forceinline__ void gld_lds(const void* g, void* l) {
  __builtin_amdgcn_global_load_lds((gas_t)g, (las_t)l, 16, 0, 0);
}

// ---------- weight pre-swizzle into MFMA B-fragment order ----------
// B-frag element: n = lane&15, k = (lane>>4)*8 + j
__global__ void swz_kernel(const float* __restrict__ W_in, const float* __restrict__ W_out,
                           const float* __restrict__ w_ih, const float* __restrict__ w_hh,
                           bf16_t* __restrict__ ws) {
  const int f = blockIdx.x * blockDim.x + threadIdx.x;  // frag-lane id (90112 total)
  const float* src;
  bf16_t* dst;
  if (f < 16384) {            // Wcat: (((ng*8+kb)*8+nl)*64+lane)*8
    const int l = f & 63, rem = f >> 6;
    const int nl = rem & 7, rem2 = rem >> 3, kb = rem2 & 7, ng = rem2 >> 3;
    const int c = ng * 128 + nl * 16 + (l & 15);
    const int k = kb * 32 + ((l >> 4) << 3);
    src = (c < 256) ? (W_in + c * 256 + k) : (W_out + (c - 256) * 256 + k);
    dst = ws + (size_t)OFF_WCAT / 2 + (size_t)f * 8;
  } else {                    // Wg (ct4 layout): (((ct*24+kb)*12 + g*4+nl)*64+lane)*8
    const int f2 = f - 16384;
    const int l = f2 & 63, rem = f2 >> 6;        // 0..1151
    const int fi = rem % 12, rem2 = rem / 12, kb = rem2 % 24, ct = rem2 / 24;
    const int g = fi >> 2, nl = fi & 3;
    const int rw = g * 256 + ct * 64 + nl * 16 + (l & 15);
    const int kq = (l >> 4) << 3;
    if (kb < 16) src = w_ih + rw * 512 + kb * 32 + kq;
    else         src = w_hh + rw * 256 + (kb - 16) * 32 + kq;
    dst = ws + (size_t)OFF_WG / 2 + (size_t)f2 * 8;
  }
  bf16x8 v;
  #pragma unroll
  for (int j = 0; j < 8; ++j) v[j] = (bf16_t)src[j];
  *(bf16x8*)dst = v;
}

// ---------- f32 -> bf16 conversion of hidden and A ----------
__global__ void convert_kernel(const float* __restrict__ hid, const float* __restrict__ A,
                               bf16_t* __restrict__ hb, bf16_t* __restrict__ ab) {
  const size_t i4 = ((size_t)blockIdx.x * blockDim.x + threadIdx.x) * 4;
  if (i4 < NH_EL) {
    const f32x4 v = *(const f32x4*)(hid + i4);
    bf16x4 o = {(bf16_t)v[0], (bf16_t)v[1], (bf16_t)v[2], (bf16_t)v[3]};
    *(bf16x4*)(hb + i4) = o;
  } else {
    const size_t j4 = i4 - NH_EL;
    const f32x4 v = *(const f32x4*)(A + j4);
    bf16x4 o = {(bf16_t)v[0], (bf16_t)v[1], (bf16_t)v[2], (bf16_t)v[3]};
    *(bf16x4*)(ab + j4) = o;
  }
}

// ---------- star init: star = sum_n hid*mask / sum(mask)  (f32, matches ref) ----------
__global__ void star_init_kernel(const float* __restrict__ hid, const float* __restrict__ gmask,
                                 float* __restrict__ star) {
  const int b = blockIdx.x, c = threadIdx.x;
  float len = 0.f, s = 0.f;
  for (int n = 0; n < 64; ++n) {
    const float m = gmask[(size_t)b * 64 + n];
    len += m;
    s += hid[((size_t)b * 64 + n) * 256 + c] * m;
  }
  star[(size_t)b * 256 + c] = s / len;
}

// ---------- K13: X = h@Wcat^T + b  (in LDS), then inputs = Acat@X + bias ----------
// 1D grid 4096 (XCD-chunk swizzled -> mtile, ng); 256 thr; m-tile 128 rows = 2 batches
__launch_bounds__(256, 2)
__global__ void k13_kernel(const bf16_t* __restrict__ hb, const bf16_t* __restrict__ ab,
                           const bf16_t* __restrict__ swzWcat,
                           const float* __restrict__ b_in, const float* __restrict__ b_out,
                           const float* __restrict__ b_iah, const float* __restrict__ b_oah,
                           bf16_t* __restrict__ inputs) {
  extern __shared__ char lds[];
  bf16_t* stA = (bf16_t*)lds;                // 8 frags  = 8192 B
  bf16_t* stB = (bf16_t*)(lds + 8192);       // 8 frags  = 8192 B
  bf16_t* CT  = (bf16_t*)(lds + 16384);      // 128 x 136 bf16 = 34816 B (X^T)
  bf16_t* AbF = (bf16_t*)(lds + 51200);      // 16 frags = 16384 B
  // XCD-chunked swizzle: 4 ng-blocks of one mtile land adjacent on one XCD
  const int lin = blockIdx.x;
  const int vid = (lin & 7) * 512 + (lin >> 3);
  const int mtile = vid >> 2, ng = vid & 3;
  const int t = threadIdx.x, w = t >> 6, l = t & 63;
  const int q = l >> 4, l15 = l & 15;
  const int half = ng >> 1, b0 = mtile * 2;

  // stage Ab fragments for GEMM2 up front (async; barriers below cover completion)
  #pragma unroll
  for (int i = 0; i < 4; ++i) {
    const int fidx = w * 4 + i, mt = fidx >> 1, kb2 = fidx & 1;
    const int bloc = b0 + (mt >> 2), m = (mt & 3) * 16 + l15;
    const bf16_t* g = ab + ((size_t)(bloc * 64 + m) * 128 + half * 64 + kb2 * 32 + q * 8);
    gld_lds(g, AbF + fidx * 512);
  }

  // ---- GEMM1: X-tile (128 x 128), K=256 ----
  f32x4 acc[2][8] = {};
  #pragma unroll 1
  for (int kb = 0; kb < 8; ++kb) {
    #pragma unroll
    for (int i = 0; i < 4; ++i) {
      const int f = w * 4 + i;
      if (f < 8) {
        const bf16_t* g = hb + ((size_t)(mtile * 128 + f * 16 + l15) * 256 + kb * 32 + q * 8);
        gld_lds(g, stA + f * 512);
      } else {
        const int fb = f - 8;
        const bf16_t* g = swzWcat + ((size_t)(((ng * 8 + kb) * 8 + fb)) * 64 + l) * 8;
        gld_lds(g, stB + fb * 512);
      }
    }
    __syncthreads();
    const bf16x8 a0 = *(const bf16x8*)(stA + (2 * w) * 512 + l * 8);
    const bf16x8 a1 = *(const bf16x8*)(stA + (2 * w + 1) * 512 + l * 8);
    #pragma unroll
    for (int nt = 0; nt < 8; ++nt) {
      const bf16x8 bf = *(const bf16x8*)(stB + nt * 512 + l * 8);
      acc[0][nt] = mfma16(a0, bf, acc[0][nt]);
      acc[1][nt] = mfma16(a1, bf, acc[1][nt]);
    }
    __syncthreads();
  }
  // epilogue: bias + bf16, store X^T into CT
  #pragma unroll
  for (int nt = 0; nt < 8; ++nt) {
    const int cl = nt * 16 + l15, cg = ng * 128 + cl;
    const float bb = (cg < 256) ? b_in[cg] : b_out[cg - 256];
    #pragma unroll
    for (int mti = 0; mti < 2; ++mti) {
      const int kloc = w * 32 + mti * 16 + q * 4;
      bf16x4 v = {(bf16_t)(acc[mti][nt][0] + bb), (bf16_t)(acc[mti][nt][1] + bb),
                  (bf16_t)(acc[mti][nt][2] + bb), (bf16_t)(acc[mti][nt][3] + bb)};
      *(bf16x4*)(CT + cl * 136 + kloc) = v;
    }
  }
  __syncthreads();

  // ---- GEMM2: inputs-tile = Acat @ X (K=64, per-batch block) ----
  f32x4 acc2[2][8] = {};
  const int bblk = (w >> 1) * 64;
  #pragma unroll
  for (int kb2 = 0; kb2 < 2; ++kb2) {
    const bf16x8 a0 = *(const bf16x8*)(AbF + ((2 * w) * 2 + kb2) * 512 + l * 8);
    const bf16x8 a1 = *(const bf16x8*)(AbF + ((2 * w + 1) * 2 + kb2) * 512 + l * 8);
    #pragma unroll
    for (int nt = 0; nt < 8; ++nt) {
      const bf16x8 bf = *(const bf16x8*)(CT + (nt * 16 + l15) * 136 + bblk + kb2 * 32 + q * 8);
      acc2[0][nt] = mfma16(a0, bf, acc2[0][nt]);
      acc2[1][nt] = mfma16(a1, bf, acc2[1][nt]);
    }
  }
  const int bglob = b0 + (w >> 1);
  #pragma unroll
  for (int nt = 0; nt < 8; ++nt) {
    const int c512 = ng * 128 + nt * 16 + l15;
    const float bb = (c512 < 256) ? b_iah[c512] : b_oah[c512 - 256];
    #pragma unroll
    for (int mti = 0; mti < 2; ++mti)
      #pragma unroll
      for (int i = 0; i < 4; ++i) {
        const int mloc = (w & 1) * 32 + mti * 16 + q * 4 + i;
        inputs[((size_t)(bglob * 64 + mloc)) * 512 + c512] = (bf16_t)(acc2[mti][nt][i] + bb);
      }
  }
}

// ---------- K3: gates GEMM (K=512 inputs + 256 h) + GRU update ----------
// 1D grid 4096 (XCD-chunk swizzled -> mtile, ct of 4); 256 thr; N-tile 64 H-cols
// v3: double-buffered LDS, single raw barrier per K-step (T3-minimum 2-phase),
//     2x2 wave split (64 rows x 96 cols per wave) -> 10 ds_reads / 24 MFMA per wave
__launch_bounds__(256, 2)
__global__ void k3_kernel(const bf16_t* __restrict__ inputs, const bf16_t* __restrict__ hb,
                          const bf16_t* __restrict__ swzWg,
                          const float* __restrict__ b_ih, const float* __restrict__ b_hh,
                          bf16_t* __restrict__ hb2) {
  extern __shared__ char lds[];
  bf16_t* stA0 = (bf16_t*)lds;               // 8 frags  = 8192 B
  bf16_t* stB0 = (bf16_t*)(lds + 8192);      // 12 frags = 12288 B
  bf16_t* stA1 = (bf16_t*)(lds + 20480);
  bf16_t* stB1 = (bf16_t*)(lds + 28672);     // total 40960 B
  // XCD-chunked swizzle: 4 ct-blocks of one mtile land adjacent on one XCD
  const int lin = blockIdx.x;
  const int vid = (lin & 7) * 512 + (lin >> 3);
  const int mtile = vid >> 2, ct = vid & 3;
  const int t = threadIdx.x, w = t >> 6, l = t & 63;
  const int q = l >> 4, l15 = l & 15;
  const int wm = w >> 1, wn = w & 1;

  f32x4 accR[4][2] = {}, accZ[4][2] = {}, accNI[4][2] = {}, accNH[4][2] = {};

  // stage one K-step (20 frags, 5 per wave: 8 A + 12 B)
  auto stage = [&](int kb, bf16_t* sa, bf16_t* sb) {
    #pragma unroll
    for (int i = 0; i < 5; ++i) {
      const int fid = w * 5 + i;
      if (fid < 8) {
        const int row = mtile * 128 + fid * 16 + l15;
        const bf16_t* g = (kb < 16)
          ? inputs + ((size_t)row * 512 + kb * 32 + q * 8)
          : hb + ((size_t)row * 256 + (kb - 16) * 32 + q * 8);
        gld_lds(g, sa + fid * 512);
      } else {
        const int fb = fid - 8;
        const bf16_t* g = swzWg + ((size_t)((ct * 24 + kb) * 12 + fb) * 64 + l) * 8;
        gld_lds(g, sb + fb * 512);
      }
    }
  };

  auto compute = [&](int kb, const bf16_t* sa, const bf16_t* sb) {
    bf16x8 a[4];
    #pragma unroll
    for (int mti = 0; mti < 4; ++mti)
      a[mti] = *(const bf16x8*)(sa + (wm * 4 + mti) * 512 + l * 8);
    #pragma unroll
    for (int g3 = 0; g3 < 3; ++g3)
      #pragma unroll
      for (int nl = 0; nl < 2; ++nl) {
        const bf16x8 bf = *(const bf16x8*)(sb + (g3 * 4 + wn * 2 + nl) * 512 + l * 8);
        #pragma unroll
        for (int mti = 0; mti < 4; ++mti) {
          if (g3 == 0)      accR[mti][nl] = mfma16(a[mti], bf, accR[mti][nl]);
          else if (g3 == 1) accZ[mti][nl] = mfma16(a[mti], bf, accZ[mti][nl]);
          else if (kb < 16) accNI[mti][nl] = mfma16(a[mti], bf, accNI[mti][nl]);
          else              accNH[mti][nl] = mfma16(a[mti], bf, accNH[mti][nl]);
        }
      }
  };

  stage(0, stA0, stB0);
  asm volatile("s_waitcnt vmcnt(0)" ::: "memory");
  __builtin_amdgcn_s_barrier();
  #pragma unroll 1
  for (int kbp = 0; kbp < 12; ++kbp) {
    const int kb = 2 * kbp;
    // phase even: prefetch kb+1 -> buf1, compute kb from buf0
    stage(kb + 1, stA1, stB1);
    compute(kb, stA0, stB0);
    asm volatile("s_waitcnt vmcnt(0)" ::: "memory");
    __builtin_amdgcn_s_barrier();
    // phase odd: prefetch kb+2 -> buf0, compute kb+1 from buf1
    if (kbp < 11) stage(kb + 2, stA0, stB0);
    compute(kb + 1, stA1, stB1);
    asm volatile("s_waitcnt vmcnt(0)" ::: "memory");
    __builtin_amdgcn_s_barrier();
  }

  // epilogue: gates + GRU
  #pragma unroll
  for (int nl = 0; nl < 2; ++nl) {
    const int c = ct * 64 + (wn * 2 + nl) * 16 + l15;
    const float brv = b_ih[c] + b_hh[c];
    const float bzv = b_ih[256 + c] + b_hh[256 + c];
    const float biv = b_ih[512 + c];
    const float bhv = b_hh[512 + c];
    #pragma unroll
    for (int mti = 0; mti < 4; ++mti)
      #pragma unroll
      for (int i = 0; i < 4; ++i) {
        const size_t m = (size_t)mtile * 128 + wm * 64 + mti * 16 + q * 4 + i;
        const float r = sigm_(accR[mti][nl][i] + brv);
        const float z = sigm_(accZ[mti][nl][i] + bzv);
        const float nn = tanh_(accNI[mti][nl][i] + biv + r * (accNH[mti][nl][i] + bhv));
        const float ho = (float)hb[m * 256 + c];
        hb2[m * 256 + c] = (bf16_t)(nn + z * (ho - nn));
      }
  }
}

// ---------- K4: attention mix + star update (per batch) ----------
__launch_bounds__(256, 2)
__global__ void k4_kernel(const bf16_t* __restrict__ hsrc, const float* __restrict__ star_in,
                          const float* __restrict__ gmask,
                          bf16_t* __restrict__ hb_out, float* __restrict__ star_out,
                          float* __restrict__ out_h, float* __restrict__ out_star,
                          const int is_last) {
  __shared__ bf16_t lhm[64 * 264];
  __shared__ float le[64];
  const int b = blockIdx.x, t = threadIdx.x;
  const int n = t >> 2, qq = t & 3, cbase = qq * 64;

  float hv[64], sv[64];
  float dot = 0.f;
  #pragma unroll
  for (int j = 0; j < 8; ++j) {
    const bf16x8 v = *(const bf16x8*)(hsrc + ((size_t)b * 64 + n) * 256 + cbase + j * 8);
    #pragma unroll
    for (int i = 0; i < 8; ++i) hv[j * 8 + i] = (float)v[i];
  }
  #pragma unroll
  for (int j = 0; j < 16; ++j) {
    const f32x4 s4 = *(const f32x4*)(star_in + (size_t)b * 256 + cbase + j * 4);
    sv[j * 4 + 0] = s4[0]; sv[j * 4 + 1] = s4[1]; sv[j * 4 + 2] = s4[2]; sv[j * 4 + 3] = s4[3];
  }
  #pragma unroll
  for (int i = 0; i < 64; ++i) dot += hv[i] * sv[i];
  dot += __shfl_xor(dot, 1); dot += __shfl_xor(dot, 2);
  const float alpha = sigm_(dot * 0.0625f);
  float dot2 = 0.f;
  #pragma unroll
  for (int i = 0; i < 64; ++i) {
    hv[i] = (1.f - alpha) * hv[i] + alpha * sv[i];
    dot2 += hv[i] * sv[i];
  }
  dot2 += __shfl_xor(dot2, 1); dot2 += __shfl_xor(dot2, 2);
  const float e = __expf(dot2) * gmask[(size_t)b * 64 + n];
  if (qq == 0) le[n] = e;
  // store mixed h (bf16 into LDS for star; global out per step)
  #pragma unroll
  for (int j = 0; j < 8; ++j) {
    bf16x8 v;
    #pragma unroll
    for (int i = 0; i < 8; ++i) v[i] = (bf16_t)hv[j * 8 + i];
    *(bf16x8*)(lhm + n * 264 + cbase + j * 8) = v;
    if (is_last) {
      f32x4 o = {hv[j * 8 + 0], hv[j * 8 + 1], hv[j * 8 + 2], hv[j * 8 + 3]};
      f32x4 o2 = {hv[j * 8 + 4], hv[j * 8 + 5], hv[j * 8 + 6], hv[j * 8 + 7]};
      *(f32x4*)(out_h + ((size_t)b * 64 + n) * 256 + cbase + j * 8) = o;
      *(f32x4*)(out_h + ((size_t)b * 64 + n) * 256 + cbase + j * 8 + 4) = o2;
    } else {
      *(bf16x8*)(hb_out + ((size_t)b * 64 + n) * 256 + cbase + j * 8) = v;
    }
  }
  __syncthreads();
  float den = 1e-24f;
  for (int n2 = 0; n2 < 64; ++n2) den += le[n2];
  const int c = t;  // 0..255
  float s = 0.f;
  for (int n2 = 0; n2 < 64; ++n2) s += le[n2] * (float)lhm[n2 * 264 + c];
  const float sn = s / den;
  if (is_last) out_star[(size_t)b * 256 + c] = sn;
  else         star_out[(size_t)b * 256 + c] = sn;
}

extern "C" void kernel_launch(void* const* d_in, const int* in_sizes, int n_in,
                              void* d_out, int out_size, void* d_ws, size_t ws_size,
                              hipStream_t stream) {
  const float* A     = (const float*)d_in[0];
  const float* hid   = (const float*)d_in[1];
  const float* gmask = (const float*)d_in[2];
  const float* w_ih  = (const float*)d_in[3];
  const float* w_hh  = (const float*)d_in[4];
  const float* b_ih  = (const float*)d_in[5];
  const float* b_hh  = (const float*)d_in[6];
  const float* b_iah = (const float*)d_in[7];
  const float* b_oah = (const float*)d_in[8];
  const float* W_in  = (const float*)d_in[9];
  const float* b_in  = (const float*)d_in[10];
  const float* W_out = (const float*)d_in[11];
  const float* b_out = (const float*)d_in[12];
  float* out = (float*)d_out;
  char* ws = (char*)d_ws;

  bf16_t* swzWcat = (bf16_t*)(ws + OFF_WCAT);
  bf16_t* swzWg   = (bf16_t*)(ws + OFF_WG);
  bf16_t* ab      = (bf16_t*)(ws + OFF_AB);
  bf16_t* hb      = (bf16_t*)(ws + OFF_HB);
  bf16_t* hb2     = (bf16_t*)(ws + OFF_HB2);
  bf16_t* inputs  = (bf16_t*)(ws + OFF_INP);
  float*  starA   = (float*)(ws + OFF_STA);
  float*  starB   = (float*)(ws + OFF_STB);
  float* out_h    = out;
  float* out_star = out + (size_t)B_SZ * N_SZ * H_SZ;

  (void)hipFuncSetAttribute((const void*)k13_kernel,
                            hipFuncAttributeMaxDynamicSharedMemorySize, 67584);

  swz_kernel<<<352, 256, 0, stream>>>(W_in, W_out, w_ih, w_hh, (bf16_t*)ws);
  convert_kernel<<<49152, 256, 0, stream>>>(hid, A, hb, ab);
  star_init_kernel<<<2048, 256, 0, stream>>>(hid, gmask, starA);

  // step 0
  k13_kernel<<<4096, 256, 67584, stream>>>(hb, ab, swzWcat, b_in, b_out, b_iah, b_oah, inputs);
  k3_kernel<<<4096, 256, 40960, stream>>>(inputs, hb, swzWg, b_ih, b_hh, hb2);
  k4_kernel<<<2048, 256, 0, stream>>>(hb2, starA, gmask, hb, starB, out_h, out_star, 0);
  // step 1
  k13_kernel<<<4096, 256, 67584, stream>>>(hb, ab, swzWcat, b_in, b_out, b_iah, b_oah, inputs);
  k3_kernel<<<4096, 256, 40960, stream>>>(inputs, hb, swzWg, b_ih, b_hh, hb2);
  k4_kernel<<<2048, 256, 0, stream>>>(hb2, starB, gmask, hb, starA, out_h, out_star, 1);
}

// Round 4
// 1072.008 us; speedup vs baseline: 1.1506x; 1.0246x over previous
//
#include <hip/hip_runtime.h>

#define B_SZ 2048
#define N_SZ 64
#define H_SZ 256

typedef __bf16 bf16_t;
typedef bf16_t bf16x8 __attribute__((ext_vector_type(8)));
typedef bf16_t bf16x4 __attribute__((ext_vector_type(4)));
typedef float  f32x4  __attribute__((ext_vector_type(4)));

// ---- workspace layout (bytes) ----
#define OFF_WCAT 0                    // swz Wcat B-frags: 512x256 bf16
#define OFF_WG   262144               // swz gate weights: 768x768 bf16
#define OFF_AB   1441792              // Ab bf16 2048x64x128
#define OFF_HB   34996224             // hb bf16 2048x64x256
#define OFF_HB2  102105088            // hb2 bf16
#define OFF_INP  169213952            // inputs bf16 2048x64x512
#define OFF_STA  303431680            // starA f32 2048x256
#define OFF_STB  305528832            // starB f32

#define NH_EL 33554432   // 2048*64*256
#define NA_EL 16777216   // 2048*64*128

__device__ __forceinline__ f32x4 mfma16(bf16x8 a, bf16x8 b, f32x4 c) {
  return __builtin_amdgcn_mfma_f32_16x16x32_bf16(a, b, c, 0, 0, 0);
}
__device__ __forceinline__ float sigm_(float x) { return 1.0f / (1.0f + __expf(-x)); }
__device__ __forceinline__ float tanh_(float x) { return 2.0f / (1.0f + __expf(-2.0f * x)) - 1.0f; }

typedef const uint32_t __attribute__((address_space(1)))* gas_t;
typedef uint32_t __attribute__((address_space(3)))* las_t;
// async global->LDS, 16 B/lane; LDS dst = wave-uniform base + lane*16
__device__ __forceinline__ void gld_lds(const void* g, void* l) {
  __builtin_amdgcn_global_load_lds((gas_t)g, (las_t)l, 16, 0, 0);
}

// ---------- weight pre-swizzle into MFMA B-fragment order ----------
// B-frag element: n = lane&15, k = (lane>>4)*8 + j
__global__ void swz_kernel(const float* __restrict__ W_in, const float* __restrict__ W_out,
                           const float* __restrict__ w_ih, const float* __restrict__ w_hh,
                           bf16_t* __restrict__ ws) {
  const int f = blockIdx.x * blockDim.x + threadIdx.x;  // frag-lane id (90112 total)
  const float* src;
  bf16_t* dst;
  if (f < 16384) {            // Wcat: (((ng*8+kb)*8+nl)*64+lane)*8
    const int l = f & 63, rem = f >> 6;
    const int nl = rem & 7, rem2 = rem >> 3, kb = rem2 & 7, ng = rem2 >> 3;
    const int c = ng * 128 + nl * 16 + (l & 15);
    const int k = kb * 32 + ((l >> 4) << 3);
    src = (c < 256) ? (W_in + c * 256 + k) : (W_out + (c - 256) * 256 + k);
    dst = ws + (size_t)OFF_WCAT / 2 + (size_t)f * 8;
  } else {                    // Wg (ct4 layout): (((ct*24+kb)*12 + g*4+nl)*64+lane)*8
    const int f2 = f - 16384;
    const int l = f2 & 63, rem = f2 >> 6;        // 0..1151
    const int fi = rem % 12, rem2 = rem / 12, kb = rem2 % 24, ct = rem2 / 24;
    const int g = fi >> 2, nl = fi & 3;
    const int rw = g * 256 + ct * 64 + nl * 16 + (l & 15);
    const int kq = (l >> 4) << 3;
    if (kb < 16) src = w_ih + rw * 512 + kb * 32 + kq;
    else         src = w_hh + rw * 256 + (kb - 16) * 32 + kq;
    dst = ws + (size_t)OFF_WG / 2 + (size_t)f2 * 8;
  }
  bf16x8 v;
  #pragma unroll
  for (int j = 0; j < 8; ++j) v[j] = (bf16_t)src[j];
  *(bf16x8*)dst = v;
}

// ---------- f32 -> bf16 conversion of hidden and A ----------
__global__ void convert_kernel(const float* __restrict__ hid, const float* __restrict__ A,
                               bf16_t* __restrict__ hb, bf16_t* __restrict__ ab) {
  const size_t i4 = ((size_t)blockIdx.x * blockDim.x + threadIdx.x) * 4;
  if (i4 < NH_EL) {
    const f32x4 v = *(const f32x4*)(hid + i4);
    bf16x4 o = {(bf16_t)v[0], (bf16_t)v[1], (bf16_t)v[2], (bf16_t)v[3]};
    *(bf16x4*)(hb + i4) = o;
  } else {
    const size_t j4 = i4 - NH_EL;
    const f32x4 v = *(const f32x4*)(A + j4);
    bf16x4 o = {(bf16_t)v[0], (bf16_t)v[1], (bf16_t)v[2], (bf16_t)v[3]};
    *(bf16x4*)(ab + j4) = o;
  }
}

// ---------- star init: star = sum_n hid*mask / sum(mask)  (f32, matches ref) ----------
__global__ void star_init_kernel(const float* __restrict__ hid, const float* __restrict__ gmask,
                                 float* __restrict__ star) {
  const int b = blockIdx.x, c = threadIdx.x;
  float len = 0.f, s = 0.f;
  for (int n = 0; n < 64; ++n) {
    const float m = gmask[(size_t)b * 64 + n];
    len += m;
    s += hid[((size_t)b * 64 + n) * 256 + c] * m;
  }
  star[(size_t)b * 256 + c] = s / len;
}

// ---------- K13: X = h@Wcat^T + b  (in LDS), then inputs = Acat@X + bias ----------
// 1D grid 4096 (XCD-chunk swizzled -> mtile, ng); 256 thr; m-tile 128 rows = 2 batches
__launch_bounds__(256, 2)
__global__ void k13_kernel(const bf16_t* __restrict__ hb, const bf16_t* __restrict__ ab,
                           const bf16_t* __restrict__ swzWcat,
                           const float* __restrict__ b_in, const float* __restrict__ b_out,
                           const float* __restrict__ b_iah, const float* __restrict__ b_oah,
                           bf16_t* __restrict__ inputs) {
  extern __shared__ char lds[];
  bf16_t* stA = (bf16_t*)lds;                // 8 frags  = 8192 B
  bf16_t* stB = (bf16_t*)(lds + 8192);       // 8 frags  = 8192 B
  bf16_t* CT  = (bf16_t*)(lds + 16384);      // 128 x 136 bf16 = 34816 B (X^T)
  bf16_t* AbF = (bf16_t*)(lds + 51200);      // 16 frags = 16384 B
  // XCD-chunked swizzle: 4 ng-blocks of one mtile land adjacent on one XCD
  const int lin = blockIdx.x;
  const int vid = (lin & 7) * 512 + (lin >> 3);
  const int mtile = vid >> 2, ng = vid & 3;
  const int t = threadIdx.x, w = t >> 6, l = t & 63;
  const int q = l >> 4, l15 = l & 15;
  const int half = ng >> 1, b0 = mtile * 2;

  // stage Ab fragments for GEMM2 up front (async; barriers below cover completion)
  #pragma unroll
  for (int i = 0; i < 4; ++i) {
    const int fidx = w * 4 + i, mt = fidx >> 1, kb2 = fidx & 1;
    const int bloc = b0 + (mt >> 2), m = (mt & 3) * 16 + l15;
    const bf16_t* g = ab + ((size_t)(bloc * 64 + m) * 128 + half * 64 + kb2 * 32 + q * 8);
    gld_lds(g, AbF + fidx * 512);
  }

  // ---- GEMM1: X-tile (128 x 128), K=256 ----
  f32x4 acc[2][8] = {};
  #pragma unroll 1
  for (int kb = 0; kb < 8; ++kb) {
    #pragma unroll
    for (int i = 0; i < 4; ++i) {
      const int f = w * 4 + i;
      if (f < 8) {
        const bf16_t* g = hb + ((size_t)(mtile * 128 + f * 16 + l15) * 256 + kb * 32 + q * 8);
        gld_lds(g, stA + f * 512);
      } else {
        const int fb = f - 8;
        const bf16_t* g = swzWcat + ((size_t)(((ng * 8 + kb) * 8 + fb)) * 64 + l) * 8;
        gld_lds(g, stB + fb * 512);
      }
    }
    __syncthreads();
    const bf16x8 a0 = *(const bf16x8*)(stA + (2 * w) * 512 + l * 8);
    const bf16x8 a1 = *(const bf16x8*)(stA + (2 * w + 1) * 512 + l * 8);
    #pragma unroll
    for (int nt = 0; nt < 8; ++nt) {
      const bf16x8 bf = *(const bf16x8*)(stB + nt * 512 + l * 8);
      acc[0][nt] = mfma16(a0, bf, acc[0][nt]);
      acc[1][nt] = mfma16(a1, bf, acc[1][nt]);
    }
    __syncthreads();
  }
  // epilogue: bias + bf16, store X^T into CT
  #pragma unroll
  for (int nt = 0; nt < 8; ++nt) {
    const int cl = nt * 16 + l15, cg = ng * 128 + cl;
    const float bb = (cg < 256) ? b_in[cg] : b_out[cg - 256];
    #pragma unroll
    for (int mti = 0; mti < 2; ++mti) {
      const int kloc = w * 32 + mti * 16 + q * 4;
      bf16x4 v = {(bf16_t)(acc[mti][nt][0] + bb), (bf16_t)(acc[mti][nt][1] + bb),
                  (bf16_t)(acc[mti][nt][2] + bb), (bf16_t)(acc[mti][nt][3] + bb)};
      *(bf16x4*)(CT + cl * 136 + kloc) = v;
    }
  }
  __syncthreads();

  // ---- GEMM2: inputs-tile = Acat @ X (K=64, per-batch block) ----
  f32x4 acc2[2][8] = {};
  const int bblk = (w >> 1) * 64;
  #pragma unroll
  for (int kb2 = 0; kb2 < 2; ++kb2) {
    const bf16x8 a0 = *(const bf16x8*)(AbF + ((2 * w) * 2 + kb2) * 512 + l * 8);
    const bf16x8 a1 = *(const bf16x8*)(AbF + ((2 * w + 1) * 2 + kb2) * 512 + l * 8);
    #pragma unroll
    for (int nt = 0; nt < 8; ++nt) {
      const bf16x8 bf = *(const bf16x8*)(CT + (nt * 16 + l15) * 136 + bblk + kb2 * 32 + q * 8);
      acc2[0][nt] = mfma16(a0, bf, acc2[0][nt]);
      acc2[1][nt] = mfma16(a1, bf, acc2[1][nt]);
    }
  }
  const int bglob = b0 + (w >> 1);
  #pragma unroll
  for (int nt = 0; nt < 8; ++nt) {
    const int c512 = ng * 128 + nt * 16 + l15;
    const float bb = (c512 < 256) ? b_iah[c512] : b_oah[c512 - 256];
    #pragma unroll
    for (int mti = 0; mti < 2; ++mti)
      #pragma unroll
      for (int i = 0; i < 4; ++i) {
        const int mloc = (w & 1) * 32 + mti * 16 + q * 4 + i;
        inputs[((size_t)(bglob * 64 + mloc)) * 512 + c512] = (bf16_t)(acc2[mti][nt][i] + bb);
      }
  }
}

// ---------- K3: gates GEMM (K=512 inputs + 256 h) + GRU update ----------
// 1D grid 4096 (XCD-chunk swizzled -> mtile, ct of 4); 256 thr; N-tile 64 H-cols
// v4: TRIPLE-buffered LDS + counted vmcnt(5) (T4) -> loads get 2 full phases to land.
//     One fused waitcnt+s_barrier per phase; 2x2 wave split unchanged.
__launch_bounds__(256, 2)
__global__ void k3_kernel(const bf16_t* __restrict__ inputs, const bf16_t* __restrict__ hb,
                          const bf16_t* __restrict__ swzWg,
                          const float* __restrict__ b_ih, const float* __restrict__ b_hh,
                          bf16_t* __restrict__ hb2) {
  extern __shared__ char lds[];
  bf16_t* A0 = (bf16_t*)lds;               // 8 frags  = 8192 B
  bf16_t* B0 = (bf16_t*)(lds + 8192);      // 12 frags = 12288 B
  bf16_t* A1 = (bf16_t*)(lds + 20480);
  bf16_t* B1 = (bf16_t*)(lds + 28672);
  bf16_t* A2 = (bf16_t*)(lds + 40960);
  bf16_t* B2 = (bf16_t*)(lds + 49152);     // total 61440 B
  // XCD-chunked swizzle: 4 ct-blocks of one mtile land adjacent on one XCD
  const int lin = blockIdx.x;
  const int vid = (lin & 7) * 512 + (lin >> 3);
  const int mtile = vid >> 2, ct = vid & 3;
  const int t = threadIdx.x, w = t >> 6, l = t & 63;
  const int q = l >> 4, l15 = l & 15;
  const int wm = w >> 1, wn = w & 1;

  f32x4 accR[4][2] = {}, accZ[4][2] = {}, accNI[4][2] = {}, accNH[4][2] = {};

  // stage one K-step: 20 frags, exactly 5 gld_lds per wave (vmcnt counts depend on this)
  auto stage = [&](int kb, bf16_t* sa, bf16_t* sb) {
    #pragma unroll
    for (int i = 0; i < 5; ++i) {
      const int fid = w * 5 + i;
      if (fid < 8) {
        const int row = mtile * 128 + fid * 16 + l15;
        const bf16_t* g = (kb < 16)
          ? inputs + ((size_t)row * 512 + kb * 32 + q * 8)
          : hb + ((size_t)row * 256 + (kb - 16) * 32 + q * 8);
        gld_lds(g, sa + fid * 512);
      } else {
        const int fb = fid - 8;
        const bf16_t* g = swzWg + ((size_t)((ct * 24 + kb) * 12 + fb) * 64 + l) * 8;
        gld_lds(g, sb + fb * 512);
      }
    }
  };

  auto compute = [&](int kb, const bf16_t* sa, const bf16_t* sb) {
    bf16x8 a[4];
    #pragma unroll
    for (int mti = 0; mti < 4; ++mti)
      a[mti] = *(const bf16x8*)(sa + (wm * 4 + mti) * 512 + l * 8);
    #pragma unroll
    for (int g3 = 0; g3 < 3; ++g3)
      #pragma unroll
      for (int nl = 0; nl < 2; ++nl) {
        const bf16x8 bf = *(const bf16x8*)(sb + (g3 * 4 + wn * 2 + nl) * 512 + l * 8);
        #pragma unroll
        for (int mti = 0; mti < 4; ++mti) {
          if (g3 == 0)      accR[mti][nl] = mfma16(a[mti], bf, accR[mti][nl]);
          else if (g3 == 1) accZ[mti][nl] = mfma16(a[mti], bf, accZ[mti][nl]);
          else if (kb < 16) accNI[mti][nl] = mfma16(a[mti], bf, accNI[mti][nl]);
          else              accNH[mti][nl] = mfma16(a[mti], bf, accNH[mti][nl]);
        }
      }
  };

  // prologue: 2 stages in flight (10 loads/wave outstanding)
  stage(0, A0, B0);
  stage(1, A1, B1);

  // steady state: wait oldest stage (vmcnt(5)), barrier, issue stage kb+2, compute kb.
  // fused waitcnt+barrier in one asm so no memory op can slide between them.
  #pragma unroll 1
  for (int i = 0; i < 7; ++i) {
    const int kb = 3 * i;
    asm volatile("s_waitcnt vmcnt(5)\ns_barrier" ::: "memory");
    stage(kb + 2, A2, B2);
    compute(kb + 0, A0, B0);
    asm volatile("s_waitcnt vmcnt(5)\ns_barrier" ::: "memory");
    stage(kb + 3, A0, B0);
    compute(kb + 1, A1, B1);
    asm volatile("s_waitcnt vmcnt(5)\ns_barrier" ::: "memory");
    stage(kb + 4, A1, B1);
    compute(kb + 2, A2, B2);
  }
  // epilogue phases 21, 22, 23
  asm volatile("s_waitcnt vmcnt(5)\ns_barrier" ::: "memory");
  stage(23, A2, B2);
  compute(21, A0, B0);
  asm volatile("s_waitcnt vmcnt(5)\ns_barrier" ::: "memory");
  compute(22, A1, B1);
  asm volatile("s_waitcnt vmcnt(0)\ns_barrier" ::: "memory");
  compute(23, A2, B2);

  // epilogue: gates + GRU
  #pragma unroll
  for (int nl = 0; nl < 2; ++nl) {
    const int c = ct * 64 + (wn * 2 + nl) * 16 + l15;
    const float brv = b_ih[c] + b_hh[c];
    const float bzv = b_ih[256 + c] + b_hh[256 + c];
    const float biv = b_ih[512 + c];
    const float bhv = b_hh[512 + c];
    #pragma unroll
    for (int mti = 0; mti < 4; ++mti)
      #pragma unroll
      for (int i = 0; i < 4; ++i) {
        const size_t m = (size_t)mtile * 128 + wm * 64 + mti * 16 + q * 4 + i;
        const float r = sigm_(accR[mti][nl][i] + brv);
        const float z = sigm_(accZ[mti][nl][i] + bzv);
        const float nn = tanh_(accNI[mti][nl][i] + biv + r * (accNH[mti][nl][i] + bhv));
        const float ho = (float)hb[m * 256 + c];
        hb2[m * 256 + c] = (bf16_t)(nn + z * (ho - nn));
      }
  }
}

// ---------- K4: attention mix + star update (per batch) ----------
__launch_bounds__(256, 2)
__global__ void k4_kernel(const bf16_t* __restrict__ hsrc, const float* __restrict__ star_in,
                          const float* __restrict__ gmask,
                          bf16_t* __restrict__ hb_out, float* __restrict__ star_out,
                          float* __restrict__ out_h, float* __restrict__ out_star,
                          const int is_last) {
  __shared__ bf16_t lhm[64 * 264];
  __shared__ float le[64];
  const int b = blockIdx.x, t = threadIdx.x;
  const int n = t >> 2, qq = t & 3, cbase = qq * 64;

  float hv[64], sv[64];
  float dot = 0.f;
  #pragma unroll
  for (int j = 0; j < 8; ++j) {
    const bf16x8 v = *(const bf16x8*)(hsrc + ((size_t)b * 64 + n) * 256 + cbase + j * 8);
    #pragma unroll
    for (int i = 0; i < 8; ++i) hv[j * 8 + i] = (float)v[i];
  }
  #pragma unroll
  for (int j = 0; j < 16; ++j) {
    const f32x4 s4 = *(const f32x4*)(star_in + (size_t)b * 256 + cbase + j * 4);
    sv[j * 4 + 0] = s4[0]; sv[j * 4 + 1] = s4[1]; sv[j * 4 + 2] = s4[2]; sv[j * 4 + 3] = s4[3];
  }
  #pragma unroll
  for (int i = 0; i < 64; ++i) dot += hv[i] * sv[i];
  dot += __shfl_xor(dot, 1); dot += __shfl_xor(dot, 2);
  const float alpha = sigm_(dot * 0.0625f);
  float dot2 = 0.f;
  #pragma unroll
  for (int i = 0; i < 64; ++i) {
    hv[i] = (1.f - alpha) * hv[i] + alpha * sv[i];
    dot2 += hv[i] * sv[i];
  }
  dot2 += __shfl_xor(dot2, 1); dot2 += __shfl_xor(dot2, 2);
  const float e = __expf(dot2) * gmask[(size_t)b * 64 + n];
  if (qq == 0) le[n] = e;
  // store mixed h (bf16 into LDS for star; global out per step)
  #pragma unroll
  for (int j = 0; j < 8; ++j) {
    bf16x8 v;
    #pragma unroll
    for (int i = 0; i < 8; ++i) v[i] = (bf16_t)hv[j * 8 + i];
    *(bf16x8*)(lhm + n * 264 + cbase + j * 8) = v;
    if (is_last) {
      f32x4 o = {hv[j * 8 + 0], hv[j * 8 + 1], hv[j * 8 + 2], hv[j * 8 + 3]};
      f32x4 o2 = {hv[j * 8 + 4], hv[j * 8 + 5], hv[j * 8 + 6], hv[j * 8 + 7]};
      *(f32x4*)(out_h + ((size_t)b * 64 + n) * 256 + cbase + j * 8) = o;
      *(f32x4*)(out_h + ((size_t)b * 64 + n) * 256 + cbase + j * 8 + 4) = o2;
    } else {
      *(bf16x8*)(hb_out + ((size_t)b * 64 + n) * 256 + cbase + j * 8) = v;
    }
  }
  __syncthreads();
  float den = 1e-24f;
  for (int n2 = 0; n2 < 64; ++n2) den += le[n2];
  const int c = t;  // 0..255
  float s = 0.f;
  for (int n2 = 0; n2 < 64; ++n2) s += le[n2] * (float)lhm[n2 * 264 + c];
  const float sn = s / den;
  if (is_last) out_star[(size_t)b * 256 + c] = sn;
  else         star_out[(size_t)b * 256 + c] = sn;
}

extern "C" void kernel_launch(void* const* d_in, const int* in_sizes, int n_in,
                              void* d_out, int out_size, void* d_ws, size_t ws_size,
                              hipStream_t stream) {
  const float* A     = (const float*)d_in[0];
  const float* hid   = (const float*)d_in[1];
  const float* gmask = (const float*)d_in[2];
  const float* w_ih  = (const float*)d_in[3];
  const float* w_hh  = (const float*)d_in[4];
  const float* b_ih  = (const float*)d_in[5];
  const float* b_hh  = (const float*)d_in[6];
  const float* b_iah = (const float*)d_in[7];
  const float* b_oah = (const float*)d_in[8];
  const float* W_in  = (const float*)d_in[9];
  const float* b_in  = (const float*)d_in[10];
  const float* W_out = (const float*)d_in[11];
  const float* b_out = (const float*)d_in[12];
  float* out = (float*)d_out;
  char* ws = (char*)d_ws;

  bf16_t* swzWcat = (bf16_t*)(ws + OFF_WCAT);
  bf16_t* swzWg   = (bf16_t*)(ws + OFF_WG);
  bf16_t* ab      = (bf16_t*)(ws + OFF_AB);
  bf16_t* hb      = (bf16_t*)(ws + OFF_HB);
  bf16_t* hb2     = (bf16_t*)(ws + OFF_HB2);
  bf16_t* inputs  = (bf16_t*)(ws + OFF_INP);
  float*  starA   = (float*)(ws + OFF_STA);
  float*  starB   = (float*)(ws + OFF_STB);
  float* out_h    = out;
  float* out_star = out + (size_t)B_SZ * N_SZ * H_SZ;

  (void)hipFuncSetAttribute((const void*)k13_kernel,
                            hipFuncAttributeMaxDynamicSharedMemorySize, 67584);
  (void)hipFuncSetAttribute((const void*)k3_kernel,
                            hipFuncAttributeMaxDynamicSharedMemorySize, 61440);

  swz_kernel<<<352, 256, 0, stream>>>(W_in, W_out, w_ih, w_hh, (bf16_t*)ws);
  convert_kernel<<<49152, 256, 0, stream>>>(hid, A, hb, ab);
  star_init_kernel<<<2048, 256, 0, stream>>>(hid, gmask, starA);

  // step 0
  k13_kernel<<<4096, 256, 67584, stream>>>(hb, ab, swzWcat, b_in, b_out, b_iah, b_oah, inputs);
  k3_kernel<<<4096, 256, 61440, stream>>>(inputs, hb, swzWg, b_ih, b_hh, hb2);
  k4_kernel<<<2048, 256, 0, stream>>>(hb2, starA, gmask, hb, starB, out_h, out_star, 0);
  // step 1
  k13_kernel<<<4096, 256, 67584, stream>>>(hb, ab, swzWcat, b_in, b_out, b_iah, b_oah, inputs);
  k3_kernel<<<4096, 256, 61440, stream>>>(inputs, hb, swzWg, b_ih, b_hh, hb2);
  k4_kernel<<<2048, 256, 0, stream>>>(hb2, starB, gmask, hb, starA, out_h, out_star, 1);
}

// Round 7
// 1060.633 us; speedup vs baseline: 1.1630x; 1.0107x over previous
//
#include <hip/hip_runtime.h>

#define B_SZ 2048
#define N_SZ 64
#define H_SZ 256

typedef __bf16 bf16_t;
typedef bf16_t bf16x8 __attribute__((ext_vector_type(8)));
typedef bf16_t bf16x4 __attribute__((ext_vector_type(4)));
typedef float  f32x4  __attribute__((ext_vector_type(4)));

// ---- workspace layout (bytes) ----
#define OFF_WCAT 0                    // swz Wcat B-frags: 512x256 bf16
#define OFF_WG   262144               // swz gate weights: 768x768 bf16
#define OFF_AB   1441792              // Ab bf16 2048x64x128
#define OFF_HB   34996224             // hb bf16 2048x64x256
#define OFF_HB2  102105088            // hb2 bf16
#define OFF_INP  169213952            // inputs bf16 2048x64x512
#define OFF_STA  303431680            // starA f32 2048x256
#define OFF_STB  305528832            // starB f32

#define NH_EL 33554432   // 2048*64*256
#define NA_EL 16777216   // 2048*64*128

__device__ __forceinline__ f32x4 mfma16(bf16x8 a, bf16x8 b, f32x4 c) {
  return __builtin_amdgcn_mfma_f32_16x16x32_bf16(a, b, c, 0, 0, 0);
}
__device__ __forceinline__ float sigm_(float x) { return 1.0f / (1.0f + __expf(-x)); }
__device__ __forceinline__ float tanh_(float x) { return 2.0f / (1.0f + __expf(-2.0f * x)) - 1.0f; }

typedef const uint32_t __attribute__((address_space(1)))* gas_t;
typedef uint32_t __attribute__((address_space(3)))* las_t;
// async global->LDS, 16 B/lane; LDS dst = wave-uniform base + lane*16
__device__ __forceinline__ void gld_lds(const void* g, void* l) {
  __builtin_amdgcn_global_load_lds((gas_t)g, (las_t)l, 16, 0, 0);
}

// ---------- weight pre-swizzle into MFMA B-fragment order ----------
// B-frag element: n = lane&15, k = (lane>>4)*8 + j
__global__ void swz_kernel(const float* __restrict__ W_in, const float* __restrict__ W_out,
                           const float* __restrict__ w_ih, const float* __restrict__ w_hh,
                           bf16_t* __restrict__ ws) {
  const int f = blockIdx.x * blockDim.x + threadIdx.x;  // frag-lane id (90112 total)
  const float* src;
  bf16_t* dst;
  if (f < 16384) {            // Wcat: (((ng*8+kb)*8+nl)*64+lane)*8
    const int l = f & 63, rem = f >> 6;
    const int nl = rem & 7, rem2 = rem >> 3, kb = rem2 & 7, ng = rem2 >> 3;
    const int c = ng * 128 + nl * 16 + (l & 15);
    const int k = kb * 32 + ((l >> 4) << 3);
    src = (c < 256) ? (W_in + c * 256 + k) : (W_out + (c - 256) * 256 + k);
    dst = ws + (size_t)OFF_WCAT / 2 + (size_t)f * 8;
  } else {                    // Wg (ct4 layout): (((ct*24+kb)*12 + g*4+nl)*64+lane)*8
    const int f2 = f - 16384;
    const int l = f2 & 63, rem = f2 >> 6;        // 0..1151
    const int fi = rem % 12, rem2 = rem / 12, kb = rem2 % 24, ct = rem2 / 24;
    const int g = fi >> 2, nl = fi & 3;
    const int rw = g * 256 + ct * 64 + nl * 16 + (l & 15);
    const int kq = (l >> 4) << 3;
    if (kb < 16) src = w_ih + rw * 512 + kb * 32 + kq;
    else         src = w_hh + rw * 256 + (kb - 16) * 32 + kq;
    dst = ws + (size_t)OFF_WG / 2 + (size_t)f2 * 8;
  }
  bf16x8 v;
  #pragma unroll
  for (int j = 0; j < 8; ++j) v[j] = (bf16_t)src[j];
  *(bf16x8*)dst = v;
}

// ---------- f32 -> bf16 conversion of hidden and A ----------
__global__ void convert_kernel(const float* __restrict__ hid, const float* __restrict__ A,
                               bf16_t* __restrict__ hb, bf16_t* __restrict__ ab) {
  const size_t i4 = ((size_t)blockIdx.x * blockDim.x + threadIdx.x) * 4;
  if (i4 < NH_EL) {
    const f32x4 v = *(const f32x4*)(hid + i4);
    bf16x4 o = {(bf16_t)v[0], (bf16_t)v[1], (bf16_t)v[2], (bf16_t)v[3]};
    *(bf16x4*)(hb + i4) = o;
  } else {
    const size_t j4 = i4 - NH_EL;
    const f32x4 v = *(const f32x4*)(A + j4);
    bf16x4 o = {(bf16_t)v[0], (bf16_t)v[1], (bf16_t)v[2], (bf16_t)v[3]};
    *(bf16x4*)(ab + j4) = o;
  }
}

// ---------- star init: star = sum_n hid*mask / sum(mask)  (f32, matches ref) ----------
__global__ void star_init_kernel(const float* __restrict__ hid, const float* __restrict__ gmask,
                                 float* __restrict__ star) {
  const int b = blockIdx.x, c = threadIdx.x;
  float len = 0.f, s = 0.f;
  for (int n = 0; n < 64; ++n) {
    const float m = gmask[(size_t)b * 64 + n];
    len += m;
    s += hid[((size_t)b * 64 + n) * 256 + c] * m;
  }
  star[(size_t)b * 256 + c] = s / len;
}

// ---------- K13: X = h@Wcat^T + b  (in LDS), then inputs = Acat@X + bias ----------
// 1D grid 4096 (XCD-chunk swizzled -> mtile, ng); 256 thr; m-tile 128 rows = 2 batches
__launch_bounds__(256, 2)
__global__ void k13_kernel(const bf16_t* __restrict__ hb, const bf16_t* __restrict__ ab,
                           const bf16_t* __restrict__ swzWcat,
                           const float* __restrict__ b_in, const float* __restrict__ b_out,
                           const float* __restrict__ b_iah, const float* __restrict__ b_oah,
                           bf16_t* __restrict__ inputs) {
  extern __shared__ char lds[];
  bf16_t* stA = (bf16_t*)lds;                // 8 frags  = 8192 B
  bf16_t* stB = (bf16_t*)(lds + 8192);       // 8 frags  = 8192 B
  bf16_t* CT  = (bf16_t*)(lds + 16384);      // 128 x 136 bf16 = 34816 B (X^T)
  bf16_t* AbF = (bf16_t*)(lds + 51200);      // 16 frags = 16384 B
  // XCD-chunked swizzle: 4 ng-blocks of one mtile land adjacent on one XCD
  const int lin = blockIdx.x;
  const int vid = (lin & 7) * 512 + (lin >> 3);
  const int mtile = vid >> 2, ng = vid & 3;
  const int t = threadIdx.x, w = t >> 6, l = t & 63;
  const int q = l >> 4, l15 = l & 15;
  const int half = ng >> 1, b0 = mtile * 2;

  // stage Ab fragments for GEMM2 up front (async; barriers below cover completion)
  #pragma unroll
  for (int i = 0; i < 4; ++i) {
    const int fidx = w * 4 + i, mt = fidx >> 1, kb2 = fidx & 1;
    const int bloc = b0 + (mt >> 2), m = (mt & 3) * 16 + l15;
    const bf16_t* g = ab + ((size_t)(bloc * 64 + m) * 128 + half * 64 + kb2 * 32 + q * 8);
    gld_lds(g, AbF + fidx * 512);
  }

  // ---- GEMM1: X-tile (128 x 128), K=256 ----
  f32x4 acc[2][8] = {};
  #pragma unroll 1
  for (int kb = 0; kb < 8; ++kb) {
    #pragma unroll
    for (int i = 0; i < 4; ++i) {
      const int f = w * 4 + i;
      if (f < 8) {
        const bf16_t* g = hb + ((size_t)(mtile * 128 + f * 16 + l15) * 256 + kb * 32 + q * 8);
        gld_lds(g, stA + f * 512);
      } else {
        const int fb = f - 8;
        const bf16_t* g = swzWcat + ((size_t)(((ng * 8 + kb) * 8 + fb)) * 64 + l) * 8;
        gld_lds(g, stB + fb * 512);
      }
    }
    __syncthreads();
    const bf16x8 a0 = *(const bf16x8*)(stA + (2 * w) * 512 + l * 8);
    const bf16x8 a1 = *(const bf16x8*)(stA + (2 * w + 1) * 512 + l * 8);
    #pragma unroll
    for (int nt = 0; nt < 8; ++nt) {
      const bf16x8 bf = *(const bf16x8*)(stB + nt * 512 + l * 8);
      acc[0][nt] = mfma16(a0, bf, acc[0][nt]);
      acc[1][nt] = mfma16(a1, bf, acc[1][nt]);
    }
    __syncthreads();
  }
  // epilogue: bias + bf16, store X^T into CT
  #pragma unroll
  for (int nt = 0; nt < 8; ++nt) {
    const int cl = nt * 16 + l15, cg = ng * 128 + cl;
    const float bb = (cg < 256) ? b_in[cg] : b_out[cg - 256];
    #pragma unroll
    for (int mti = 0; mti < 2; ++mti) {
      const int kloc = w * 32 + mti * 16 + q * 4;
      bf16x4 v = {(bf16_t)(acc[mti][nt][0] + bb), (bf16_t)(acc[mti][nt][1] + bb),
                  (bf16_t)(acc[mti][nt][2] + bb), (bf16_t)(acc[mti][nt][3] + bb)};
      *(bf16x4*)(CT + cl * 136 + kloc) = v;
    }
  }
  __syncthreads();

  // ---- GEMM2: inputs-tile = Acat @ X (K=64, per-batch block) ----
  f32x4 acc2[2][8] = {};
  const int bblk = (w >> 1) * 64;
  #pragma unroll
  for (int kb2 = 0; kb2 < 2; ++kb2) {
    const bf16x8 a0 = *(const bf16x8*)(AbF + ((2 * w) * 2 + kb2) * 512 + l * 8);
    const bf16x8 a1 = *(const bf16x8*)(AbF + ((2 * w + 1) * 2 + kb2) * 512 + l * 8);
    #pragma unroll
    for (int nt = 0; nt < 8; ++nt) {
      const bf16x8 bf = *(const bf16x8*)(CT + (nt * 16 + l15) * 136 + bblk + kb2 * 32 + q * 8);
      acc2[0][nt] = mfma16(a0, bf, acc2[0][nt]);
      acc2[1][nt] = mfma16(a1, bf, acc2[1][nt]);
    }
  }
  const int bglob = b0 + (w >> 1);
  #pragma unroll
  for (int nt = 0; nt < 8; ++nt) {
    const int c512 = ng * 128 + nt * 16 + l15;
    const float bb = (c512 < 256) ? b_iah[c512] : b_oah[c512 - 256];
    #pragma unroll
    for (int mti = 0; mti < 2; ++mti)
      #pragma unroll
      for (int i = 0; i < 4; ++i) {
        const int mloc = (w & 1) * 32 + mti * 16 + q * 4 + i;
        inputs[((size_t)(bglob * 64 + mloc)) * 512 + c512] = (bf16_t)(acc2[mti][nt][i] + bb);
      }
  }
}

// ---------- K3: gates GEMM (K=512 inputs + 256 h) + GRU update ----------
// 1D grid 4096 (XCD-chunk swizzled -> mtile, ct of 4); 256 thr; N-tile 64 H-cols
// v5b: K64-tile sub-phased schedule (T3+T4+T5): 2x40KB buffers, per tile
//     {readS0 | MFMA | readS1 | lgkm0+bar | stage(t+2) | MFMA | vmcnt(10)+bar}.
//     LDS buffer bases computed arithmetically (no LDS-pointer arrays: addrspacecast
//     static-init is unsupported).

#define K3_BUFA(bi) ((bf16_t*)(lds + (bi) * 40960))
#define K3_BUFB(bi) ((bf16_t*)(lds + (bi) * 40960 + 16384))

// read one K32 sub-step's fragments into named registers F*
#define K3_READ(F, bi, s) \
  bf16x8 F##a[4], F##R[2], F##Z[2], F##N[2]; \
  { const bf16_t* sa_ = K3_BUFA(bi); const bf16_t* sb_ = K3_BUFB(bi); \
    _Pragma("unroll") for (int mti = 0; mti < 4; ++mti) \
      F##a[mti] = *(const bf16x8*)(sa_ + ((s) * 8 + wm * 4 + mti) * 512 + l * 8); \
    _Pragma("unroll") for (int nl = 0; nl < 2; ++nl) { \
      F##R[nl] = *(const bf16x8*)(sb_ + ((s) * 12 + wn * 2 + nl) * 512 + l * 8); \
      F##Z[nl] = *(const bf16x8*)(sb_ + ((s) * 12 + 4 + wn * 2 + nl) * 512 + l * 8); \
      F##N[nl] = *(const bf16x8*)(sb_ + ((s) * 12 + 8 + wn * 2 + nl) * 512 + l * 8); } }

#define K3_MMA(F, ACCN) \
  __builtin_amdgcn_s_setprio(1); \
  _Pragma("unroll") for (int nl = 0; nl < 2; ++nl) \
    _Pragma("unroll") for (int mti = 0; mti < 4; ++mti) { \
      accR[mti][nl] = mfma16(F##a[mti], F##R[nl], accR[mti][nl]); \
      accZ[mti][nl] = mfma16(F##a[mti], F##Z[nl], accZ[mti][nl]); \
      ACCN[mti][nl] = mfma16(F##a[mti], F##N[nl], ACCN[mti][nl]); } \
  __builtin_amdgcn_s_setprio(0);

#define K3_TILE(tt, ACCN) { \
  const int bi_ = (tt) & 1; \
  K3_READ(f0, bi_, 0) \
  K3_MMA(f0, ACCN) \
  K3_READ(f1, bi_, 1) \
  asm volatile("s_waitcnt lgkmcnt(0)" ::: "memory"); \
  __builtin_amdgcn_s_barrier(); \
  if ((tt) < 10) stage((tt) + 2, bi_); \
  K3_MMA(f1, ACCN) \
  if ((tt) < 10)       { asm volatile("s_waitcnt vmcnt(10)" ::: "memory"); } \
  else if ((tt) == 10) { asm volatile("s_waitcnt vmcnt(0)" ::: "memory"); } \
  if ((tt) < 11) __builtin_amdgcn_s_barrier(); \
}

__launch_bounds__(256, 2)
__global__ void k3_kernel(const bf16_t* __restrict__ inputs, const bf16_t* __restrict__ hb,
                          const bf16_t* __restrict__ swzWg,
                          const float* __restrict__ b_ih, const float* __restrict__ b_hh,
                          bf16_t* __restrict__ hb2) {
  extern __shared__ char lds[];
  // XCD-chunked swizzle: 4 ct-blocks of one mtile land adjacent on one XCD
  const int lin = blockIdx.x;
  const int vid = (lin & 7) * 512 + (lin >> 3);
  const int mtile = vid >> 2, ct = vid & 3;
  const int t = threadIdx.x, w = t >> 6, l = t & 63;
  const int q = l >> 4, l15 = l & 15;
  const int wm = w >> 1, wn = w & 1;

  f32x4 accR[4][2] = {}, accZ[4][2] = {}, accNI[4][2] = {}, accNH[4][2] = {};

  // stage one K64 tile (kb = 2tt, 2tt+1): 40 frags, exactly 10 gld_lds per wave
  auto stage = [&](int tt, int bi) {
    bf16_t* sa = K3_BUFA(bi);
    bf16_t* sb = K3_BUFB(bi);
    const int kb0 = tt * 2;
    #pragma unroll
    for (int i = 0; i < 10; ++i) {
      const int fid = w * 10 + i;
      if (fid < 16) {
        const int s = fid >> 3, f = fid & 7;
        const int kb = kb0 + s;
        const int row = mtile * 128 + f * 16 + l15;
        const bf16_t* g = (kb < 16)
          ? inputs + ((size_t)row * 512 + kb * 32 + q * 8)
          : hb + ((size_t)row * 256 + (kb - 16) * 32 + q * 8);
        gld_lds(g, sa + (s * 8 + f) * 512);
      } else {
        const int r = fid - 16;
        const int s = r / 12, fb = r % 12;
        const int kb = kb0 + s;
        const bf16_t* g = swzWg + ((size_t)((ct * 24 + kb) * 12 + fb) * 64 + l) * 8;
        gld_lds(g, sb + (s * 12 + fb) * 512);
      }
    }
  };

  // prologue: tiles 0 and 1 in flight
  stage(0, 0);
  stage(1, 1);
  asm volatile("s_waitcnt vmcnt(10)" ::: "memory");
  __builtin_amdgcn_s_barrier();

  // tiles 0..7: K over inputs (kb 0..15) -> accNI
  #pragma unroll 1
  for (int tt = 0; tt < 8; ++tt) {
    K3_TILE(tt, accNI)
  }
  // tiles 8..11: K over hb (kb 16..23) -> accNH
  #pragma unroll 1
  for (int tt2 = 0; tt2 < 4; ++tt2) {
    const int tt = 8 + tt2;
    K3_TILE(tt, accNH)
  }

  // epilogue: gates + GRU
  #pragma unroll
  for (int nl = 0; nl < 2; ++nl) {
    const int c = ct * 64 + (wn * 2 + nl) * 16 + l15;
    const float brv = b_ih[c] + b_hh[c];
    const float bzv = b_ih[256 + c] + b_hh[256 + c];
    const float biv = b_ih[512 + c];
    const float bhv = b_hh[512 + c];
    #pragma unroll
    for (int mti = 0; mti < 4; ++mti)
      #pragma unroll
      for (int i = 0; i < 4; ++i) {
        const size_t m = (size_t)mtile * 128 + wm * 64 + mti * 16 + q * 4 + i;
        const float r = sigm_(accR[mti][nl][i] + brv);
        const float z = sigm_(accZ[mti][nl][i] + bzv);
        const float nn = tanh_(accNI[mti][nl][i] + biv + r * (accNH[mti][nl][i] + bhv));
        const float ho = (float)hb[m * 256 + c];
        hb2[m * 256 + c] = (bf16_t)(nn + z * (ho - nn));
      }
  }
}

// ---------- K4: attention mix + star update (per batch) ----------
__launch_bounds__(256, 2)
__global__ void k4_kernel(const bf16_t* __restrict__ hsrc, const float* __restrict__ star_in,
                          const float* __restrict__ gmask,
                          bf16_t* __restrict__ hb_out, float* __restrict__ star_out,
                          float* __restrict__ out_h, float* __restrict__ out_star,
                          const int is_last) {
  __shared__ bf16_t lhm[64 * 264];
  __shared__ float le[64];
  const int b = blockIdx.x, t = threadIdx.x;
  const int n = t >> 2, qq = t & 3, cbase = qq * 64;

  float hv[64], sv[64];
  float dot = 0.f;
  #pragma unroll
  for (int j = 0; j < 8; ++j) {
    const bf16x8 v = *(const bf16x8*)(hsrc + ((size_t)b * 64 + n) * 256 + cbase + j * 8);
    #pragma unroll
    for (int i = 0; i < 8; ++i) hv[j * 8 + i] = (float)v[i];
  }
  #pragma unroll
  for (int j = 0; j < 16; ++j) {
    const f32x4 s4 = *(const f32x4*)(star_in + (size_t)b * 256 + cbase + j * 4);
    sv[j * 4 + 0] = s4[0]; sv[j * 4 + 1] = s4[1]; sv[j * 4 + 2] = s4[2]; sv[j * 4 + 3] = s4[3];
  }
  #pragma unroll
  for (int i = 0; i < 64; ++i) dot += hv[i] * sv[i];
  dot += __shfl_xor(dot, 1); dot += __shfl_xor(dot, 2);
  const float alpha = sigm_(dot * 0.0625f);
  float dot2 = 0.f;
  #pragma unroll
  for (int i = 0; i < 64; ++i) {
    hv[i] = (1.f - alpha) * hv[i] + alpha * sv[i];
    dot2 += hv[i] * sv[i];
  }
  dot2 += __shfl_xor(dot2, 1); dot2 += __shfl_xor(dot2, 2);
  const float e = __expf(dot2) * gmask[(size_t)b * 64 + n];
  if (qq == 0) le[n] = e;
  // store mixed h (bf16 into LDS for star; global out per step)
  #pragma unroll
  for (int j = 0; j < 8; ++j) {
    bf16x8 v;
    #pragma unroll
    for (int i = 0; i < 8; ++i) v[i] = (bf16_t)hv[j * 8 + i];
    *(bf16x8*)(lhm + n * 264 + cbase + j * 8) = v;
    if (is_last) {
      f32x4 o = {hv[j * 8 + 0], hv[j * 8 + 1], hv[j * 8 + 2], hv[j * 8 + 3]};
      f32x4 o2 = {hv[j * 8 + 4], hv[j * 8 + 5], hv[j * 8 + 6], hv[j * 8 + 7]};
      *(f32x4*)(out_h + ((size_t)b * 64 + n) * 256 + cbase + j * 8) = o;
      *(f32x4*)(out_h + ((size_t)b * 64 + n) * 256 + cbase + j * 8 + 4) = o2;
    } else {
      *(bf16x8*)(hb_out + ((size_t)b * 64 + n) * 256 + cbase + j * 8) = v;
    }
  }
  __syncthreads();
  float den = 1e-24f;
  for (int n2 = 0; n2 < 64; ++n2) den += le[n2];
  const int c = t;  // 0..255
  float s = 0.f;
  for (int n2 = 0; n2 < 64; ++n2) s += le[n2] * (float)lhm[n2 * 264 + c];
  const float sn = s / den;
  if (is_last) out_star[(size_t)b * 256 + c] = sn;
  else         star_out[(size_t)b * 256 + c] = sn;
}

extern "C" void kernel_launch(void* const* d_in, const int* in_sizes, int n_in,
                              void* d_out, int out_size, void* d_ws, size_t ws_size,
                              hipStream_t stream) {
  const float* A     = (const float*)d_in[0];
  const float* hid   = (const float*)d_in[1];
  const float* gmask = (const float*)d_in[2];
  const float* w_ih  = (const float*)d_in[3];
  const float* w_hh  = (const float*)d_in[4];
  const float* b_ih  = (const float*)d_in[5];
  const float* b_hh  = (const float*)d_in[6];
  const float* b_iah = (const float*)d_in[7];
  const float* b_oah = (const float*)d_in[8];
  const float* W_in  = (const float*)d_in[9];
  const float* b_in  = (const float*)d_in[10];
  const float* W_out = (const float*)d_in[11];
  const float* b_out = (const float*)d_in[12];
  float* out = (float*)d_out;
  char* ws = (char*)d_ws;

  bf16_t* swzWcat = (bf16_t*)(ws + OFF_WCAT);
  bf16_t* swzWg   = (bf16_t*)(ws + OFF_WG);
  bf16_t* ab      = (bf16_t*)(ws + OFF_AB);
  bf16_t* hb      = (bf16_t*)(ws + OFF_HB);
  bf16_t* hb2     = (bf16_t*)(ws + OFF_HB2);
  bf16_t* inputs  = (bf16_t*)(ws + OFF_INP);
  float*  starA   = (float*)(ws + OFF_STA);
  float*  starB   = (float*)(ws + OFF_STB);
  float* out_h    = out;
  float* out_star = out + (size_t)B_SZ * N_SZ * H_SZ;

  (void)hipFuncSetAttribute((const void*)k13_kernel,
                            hipFuncAttributeMaxDynamicSharedMemorySize, 67584);
  (void)hipFuncSetAttribute((const void*)k3_kernel,
                            hipFuncAttributeMaxDynamicSharedMemorySize, 81920);

  swz_kernel<<<352, 256, 0, stream>>>(W_in, W_out, w_ih, w_hh, (bf16_t*)ws);
  convert_kernel<<<49152, 256, 0, stream>>>(hid, A, hb, ab);
  star_init_kernel<<<2048, 256, 0, stream>>>(hid, gmask, starA);

  // step 0
  k13_kernel<<<4096, 256, 67584, stream>>>(hb, ab, swzWcat, b_in, b_out, b_iah, b_oah, inputs);
  k3_kernel<<<4096, 256, 81920, stream>>>(inputs, hb, swzWg, b_ih, b_hh, hb2);
  k4_kernel<<<2048, 256, 0, stream>>>(hb2, starA, gmask, hb, starB, out_h, out_star, 0);
  // step 1
  k13_kernel<<<4096, 256, 67584, stream>>>(hb, ab, swzWcat, b_in, b_out, b_iah, b_oah, inputs);
  k3_kernel<<<4096, 256, 81920, stream>>>(inputs, hb, swzWg, b_ih, b_hh, hb2);
  k4_kernel<<<2048, 256, 0, stream>>>(hb2, starB, gmask, hb, starA, out_h, out_star, 1);
}